// Round 14
// baseline (2328.024 us; speedup 1.0000x reference)
//
#include <hip/hip_runtime.h>

// RuleGraphNet: 2x TripleConv(+mlp), N=50000 nodes, E=800000 edges.
// Edge attrs gathered into CSR (dst-sorted) order as bf16[NE][128] once.
// conv_fused (one per conv): block owns 44 dst nodes; per phase, walks the
// CSR span in 128-row MFMA tiles (A direct from ebf, W from pre-transposed
// Wt), stages C in conflict-free LDS, aggregates straight out of LDS with
// register accumulators (wave owns 11 nodes, lane owns a column pair);
// NO MT materialization, no atomics. NT stored bf16; self fused into write.

#define NN 50000
#define NE 800000
#define EHALF 400000
#define NN2 100000
#define GNODES 44       // dst nodes per conv_fused block
#define NPW 11          // nodes per wave

typedef __attribute__((ext_vector_type(4))) float  f32x4;
typedef __attribute__((ext_vector_type(8))) __bf16 bf16x8;
typedef __attribute__((ext_vector_type(4))) __bf16 bf16x4;

__device__ __forceinline__ float bf16lo(unsigned u) {
    union { unsigned u; float f; } c; c.u = u << 16; return c.f;
}
__device__ __forceinline__ float bf16hi(unsigned u) {
    union { unsigned u; float f; } c; c.u = u & 0xffff0000u; return c.f;
}

// ---------------- generic bf16 MFMA GEMM (LDS-staged A, fp32 in) ----------
template<int K, bool OBF16>
__global__ __launch_bounds__(256)
void mm_bf16(const float* __restrict__ A, const float* __restrict__ W,
             const float* __restrict__ bias, void* __restrict__ Outp,
             int Kw, int M, int N, int ldo, int RT, int relu)
{
    __shared__ __align__(16) __bf16 et[128 * 128];
    const int t = threadIdx.x;
    const int lane = t & 63, w = t >> 6;
    const int mh = w & 1, nh = w >> 1;
    const int l15 = lane & 15, l4 = lane >> 4;
    const int cb = blockIdx.y * 64;

    bf16x8 wf[2][4];
    const int colbase = cb + nh * 32 + l15;
    #pragma unroll
    for (int nt = 0; nt < 2; ++nt) {
        int col = colbase + nt * 16;
        #pragma unroll
        for (int ks = 0; ks < 4; ++ks) {
            bf16x8 f;
            #pragma unroll
            for (int j = 0; j < 8; ++j) {
                int k = ks * 32 + l4 * 8 + j;
                float v = (k < Kw && col < N) ? W[k * N + col] : 0.f;
                f[j] = (__bf16)v;
            }
            wf[nt][ks] = f;
        }
    }
    float bv[2] = {0.f, 0.f};
    if (bias) {
        #pragma unroll
        for (int nt = 0; nt < 2; ++nt) {
            int col = colbase + nt * 16;
            if (col < N) bv[nt] = bias[col];
        }
    }

    for (int it = 0; it < RT; ++it) {
        const int row0 = (blockIdx.x * RT + it) * 128;
        if (row0 >= M) break;
        __syncthreads();
        if constexpr (K % 4 == 0) {
            constexpr int QK = K / 4;
            for (int i = t; i < 128 * QK; i += 256) {
                int row = i / QK, q = i - row * QK;
                int gr = row0 + row;
                float4 v = {0.f, 0.f, 0.f, 0.f};
                if (gr < M) v = *(const float4*)(A + (size_t)gr * K + q * 4);
                bf16x4 b;
                b[0] = (__bf16)v.x; b[1] = (__bf16)v.y;
                b[2] = (__bf16)v.z; b[3] = (__bf16)v.w;
                *(bf16x4*)(et + row * 128 + ((q * 4) ^ ((row & 7) << 3))) = b;
            }
            constexpr int QP = (128 - K) / 4;
            if constexpr (QP > 0) {
                for (int i = t; i < 128 * QP; i += 256) {
                    int row = i / QP, q = QK + (i - (i / QP) * QP);
                    bf16x4 z;
                    z[0] = (__bf16)0.f; z[1] = (__bf16)0.f;
                    z[2] = (__bf16)0.f; z[3] = (__bf16)0.f;
                    *(bf16x4*)(et + row * 128 + ((q * 4) ^ ((row & 7) << 3))) = z;
                }
            }
        } else {
            for (int i = t; i < 128 * 128; i += 256) {
                int row = i >> 7, k = i & 127;
                int gr = row0 + row;
                float v = (k < K && gr < M) ? A[(size_t)gr * K + k] : 0.f;
                et[row * 128 + (k ^ ((row & 7) << 3))] = (__bf16)v;
            }
        }
        __syncthreads();

        f32x4 c[4][2] = {};
        #pragma unroll
        for (int ks = 0; ks < 4; ++ks) {
            #pragma unroll
            for (int mt = 0; mt < 4; ++mt) {
                int arow = mh * 64 + mt * 16 + l15;
                bf16x8 a = *(const bf16x8*)(et + arow * 128 +
                                            ((ks * 32 + l4 * 8) ^ ((l15 & 7) << 3)));
                c[mt][0] = __builtin_amdgcn_mfma_f32_16x16x32_bf16(a, wf[0][ks], c[mt][0], 0, 0, 0);
                c[mt][1] = __builtin_amdgcn_mfma_f32_16x16x32_bf16(a, wf[1][ks], c[mt][1], 0, 0, 0);
            }
        }

        #pragma unroll
        for (int mt = 0; mt < 4; ++mt) {
            #pragma unroll
            for (int nt = 0; nt < 2; ++nt) {
                int col = colbase + nt * 16;
                #pragma unroll
                for (int r = 0; r < 4; ++r) {
                    int row = row0 + mh * 64 + mt * 16 + l4 * 4 + r;
                    if constexpr (OBF16) {
                        if (row < M && col < ldo)
                            ((__bf16*)Outp)[(size_t)row * ldo + col] =
                                (__bf16)(c[mt][nt][r] + bv[nt]);
                    } else {
                        if (row < M && col < N) {
                            float v = c[mt][nt][r] + bv[nt];
                            if (relu) v = fmaxf(v, 0.f);
                            ((float*)Outp)[(size_t)row * ldo + col] = v;
                        }
                    }
                }
            }
        }
    }
}

// ---------------- CSR build (edges sorted by dst, per half) ----------------
__global__ void zero_ints(int* __restrict__ p, int n)
{
    int i = blockIdx.x * 256 + threadIdx.x;
    if (i < n) p[i] = 0;
}

__global__ void count_edges(const int* __restrict__ dst, int* __restrict__ cnt)
{
    int e = blockIdx.x * 256 + threadIdx.x;
    if (e < NE) atomicAdd(&cnt[dst[e] + (e >= EHALF ? NN : 0)], 1);
}

__global__ void scan_blocks(const int* __restrict__ cnt, int* __restrict__ off,
                            int* __restrict__ bsum, int n)
{
    __shared__ int s[256];
    int t = threadIdx.x, g = blockIdx.x * 256 + t;
    int v = (g < n) ? cnt[g] : 0;
    s[t] = v; __syncthreads();
    for (int d = 1; d < 256; d <<= 1) {
        int add = (t >= d) ? s[t - d] : 0;
        __syncthreads();
        s[t] += add;
        __syncthreads();
    }
    if (g < n) off[g] = s[t] - v;
    if (t == 255) bsum[blockIdx.x] = s[255];
}

__global__ void scan_bsum(int* __restrict__ bsum, int nb)
{
    __shared__ int s[512];
    int t = threadIdx.x;
    int v = (t < nb) ? bsum[t] : 0;
    s[t] = v; __syncthreads();
    for (int d = 1; d < 512; d <<= 1) {
        int add = (t >= d) ? s[t - d] : 0;
        __syncthreads();
        s[t] += add;
        __syncthreads();
    }
    if (t < nb) bsum[t] = s[t] - v;
}

__global__ void scan_add(int* __restrict__ off, const int* __restrict__ bsum,
                         int* __restrict__ cur, int n)
{
    int g = blockIdx.x * 256 + threadIdx.x;
    if (g < n) { int o = off[g] + bsum[blockIdx.x]; off[g] = o; cur[g] = o; }
}

__global__ void scatter_edges(const int* __restrict__ eidx, int* __restrict__ cur,
                              int* __restrict__ srcp, int* __restrict__ eord)
{
    int e = blockIdx.x * 256 + threadIdx.x;
    if (e < NE) {
        int s = eidx[e], d = eidx[NE + e];
        int pos = atomicAdd(&cur[d + (e >= EHALF ? NN : 0)], 1);
        srcp[pos] = s;
        eord[pos] = e;
    }
}

// ------- eattr gather -> CSR-ordered bf16 [NE][128] (zero-padded) ---------
__global__ __launch_bounds__(256)
void cvt_gather(const float* __restrict__ eatt, const int* __restrict__ eord,
                __bf16* __restrict__ ebf)
{
    int i = blockIdx.x * 256 + threadIdx.x;     // NE*16 threads, 8 cols each
    int row = i >> 4, oct = i & 15;
    if (row >= NE) return;
    const float* p = eatt + (size_t)eord[row] * 100;
    bf16x8 o;
    if (oct < 12) {
        float4 v0 = *(const float4*)(p + oct * 8);
        float4 v1 = *(const float4*)(p + oct * 8 + 4);
        o[0] = (__bf16)v0.x; o[1] = (__bf16)v0.y; o[2] = (__bf16)v0.z; o[3] = (__bf16)v0.w;
        o[4] = (__bf16)v1.x; o[5] = (__bf16)v1.y; o[6] = (__bf16)v1.z; o[7] = (__bf16)v1.w;
    } else if (oct == 12) {
        float4 v0 = *(const float4*)(p + 96);
        o[0] = (__bf16)v0.x; o[1] = (__bf16)v0.y; o[2] = (__bf16)v0.z; o[3] = (__bf16)v0.w;
        o[4] = (__bf16)0.f; o[5] = (__bf16)0.f; o[6] = (__bf16)0.f; o[7] = (__bf16)0.f;
    } else {
        #pragma unroll
        for (int j = 0; j < 8; ++j) o[j] = (__bf16)0.f;
    }
    *(bf16x8*)(ebf + (size_t)row * 128 + oct * 8) = o;
}

// --------- conv_fused: edge mid-GEMM + aggregation, one conv ---------
// Block owns GNODES consecutive dst nodes. Per phase: walk the nodes' CSR
// span [pb,pe) in 128-row MFMA tiles (A from ebf, W from transposed Wt
// quarter); stage C in LDS (stride 116, conflict-free); each wave (owning
// NPW nodes) aggregates its nodes' rows straight from LDS: per edge one LDS
// u32 (C pair) + one NT[src] u32 gather; register accumulators persist
// across tiles/phases. Final write fuses self; pad cols zeroed.
template<int ND, int NTS>
__global__ __launch_bounds__(256)
void conv_fused(const __bf16* __restrict__ ebf,   // [NE+128][128] CSR order
                const __bf16* __restrict__ Wt,    // [2][128][128] phase a,b
                const int* __restrict__ srcp,     // [NE] src per CSR position
                const int* __restrict__ off,      // [NN2]
                const __bf16* __restrict__ NT,    // [NN][NTS] bf16
                const float* __restrict__ self,   // [NN][ND] fp32
                float* __restrict__ aggr,         // [NN][112]
                int blkd0, int blks0, int blkd1, int blks1)
{
    __shared__ __align__(16) __bf16 ct[128 * 116];   // 29.7 KB
    const int t = threadIdx.x;
    const int lane = t & 63, wv = t >> 6;
    const int mh = wv & 1, nq = wv >> 1;
    const int l15 = lane & 15, l4 = lane >> 4;
    const int n0 = blockIdx.x * GNODES;
    const int nend = min(n0 + GNODES, NN);
    const int nw0 = n0 + wv * NPW;
    const int c0 = lane * 2;
    const bool a0 = c0 < ND, a1 = c0 + 1 < ND;
    const int colbase = nq * 64 + l15;

    float acc0[NPW] = {}, acc1[NPW] = {};

    for (int phase = 0; phase < 2; ++phase) {
        const __bf16* Wq = Wt + (size_t)phase * 16384;
        const int blkd = phase ? blkd1 : blkd0;
        const int blks = phase ? blks1 : blks0;

        bf16x8 wf[4][4];
        #pragma unroll
        for (int nt = 0; nt < 4; ++nt)
            #pragma unroll
            for (int ks = 0; ks < 4; ++ks)
                wf[nt][ks] = *(const bf16x8*)(Wq + (colbase + nt * 16) * 128 +
                                              ks * 32 + l4 * 8);

        const int idxb = phase * NN + n0;
        const int idxe = phase * NN + nend;
        const int pb = off[idxb];
        const int pe = (idxe == NN2) ? NE : off[idxe];

        for (int pt = pb; pt < pe; pt += 128) {
            // MFMA tile: rows pt..pt+127 (rows >= pe are garbage, never read)
            f32x4 c[4][4] = {};
            #pragma unroll
            for (int ks = 0; ks < 4; ++ks) {
                #pragma unroll
                for (int mt = 0; mt < 4; ++mt) {
                    size_t row = (size_t)pt + mh * 64 + mt * 16 + l15;
                    bf16x8 a = *(const bf16x8*)(ebf + row * 128 + ks * 32 + l4 * 8);
                    #pragma unroll
                    for (int nt = 0; nt < 4; ++nt)
                        c[mt][nt] = __builtin_amdgcn_mfma_f32_16x16x32_bf16(
                            a, wf[nt][ks], c[mt][nt], 0, 0, 0);
                }
            }
            __syncthreads();   // previous tile's aggregation done
            #pragma unroll
            for (int mt = 0; mt < 4; ++mt) {
                #pragma unroll
                for (int nt = 0; nt < 4; ++nt) {
                    int col = colbase + nt * 16;
                    if (col < 112) {
                        #pragma unroll
                        for (int r = 0; r < 4; ++r) {
                            int lrow = mh * 64 + mt * 16 + l4 * 4 + r;
                            ct[lrow * 116 + col] = (__bf16)c[mt][nt][r];
                        }
                    }
                }
            }
            __syncthreads();

            // aggregation straight from LDS: wave's NPW nodes ∩ this tile
            if (a0) {
                const int tlo = pt, thi = pt + 128;
                #pragma unroll
                for (int ni = 0; ni < NPW; ++ni) {
                    int n = nw0 + ni;
                    float pa = 0.f, pbv = 0.f;
                    if (n < nend) {
                        int idxn = phase * NN + n;
                        int ps = off[idxn];
                        int idxn1 = idxn + 1;
                        int pen = (idxn1 == NN2) ? NE : off[idxn1];
                        ps = max(ps, tlo);
                        pen = min(pen, thi);
                        if (ps < pen) {
                            unsigned ndw = *(const unsigned*)(NT + (size_t)n * NTS + blkd + c0);
                            float nd0 = bf16lo(ndw), nd1 = bf16hi(ndw);
                            for (int p = ps; p < pen; p += 4) {
                                int ss[4];
                                #pragma unroll
                                for (int i = 0; i < 4; ++i) {
                                    int pp = p + i;
                                    ss[i] = (pp < pen) ? srcp[pp] : -1;
                                }
                                unsigned mtv[4], nsw[4];
                                #pragma unroll
                                for (int i = 0; i < 4; ++i) {
                                    mtv[i] = 0u; nsw[i] = 0u;
                                    if (ss[i] >= 0) {
                                        mtv[i] = *(const unsigned*)(ct + (p + i - pt) * 116 + c0);
                                        nsw[i] = *(const unsigned*)(NT + (size_t)ss[i] * NTS + blks + c0);
                                    }
                                }
                                #pragma unroll
                                for (int i = 0; i < 4; ++i) {
                                    if (ss[i] < 0) continue;   // wave-uniform
                                    pa  += fmaxf(bf16lo(mtv[i]) + nd0 + bf16lo(nsw[i]), 0.f);
                                    pbv += fmaxf(bf16hi(mtv[i]) + nd1 + bf16hi(nsw[i]), 0.f);
                                }
                            }
                        }
                    }
                    acc0[ni] += pa;
                    acc1[ni] += pbv;
                }
            }
            __syncthreads();   // ct consumed before next tile stages
        }
    }

    // write: aggr[n][0..111], pads zeroed, self fused
    if (c0 < 112) {
        #pragma unroll
        for (int ni = 0; ni < NPW; ++ni) {
            int n = nw0 + ni;
            if (n < nend) {
                const size_t g0 = (size_t)n * 112 + c0;
                aggr[g0]     = a0 ? (acc0[ni] + self[(size_t)n * ND + c0])     : 0.f;
                aggr[g0 + 1] = a1 ? (acc1[ni] + self[(size_t)n * ND + c0 + 1]) : 0.f;
            }
        }
    }
}

// ---- weight assembly: padded concat blocks + transposed mid blocks -------
__global__ void assemble(const float* __restrict__ l1a, const float* __restrict__ l1ab,
                         const float* __restrict__ l1b, const float* __restrict__ l1bb,
                         const float* __restrict__ l2a, const float* __restrict__ l2ab,
                         const float* __restrict__ l2b, const float* __restrict__ l2bb,
                         float* __restrict__ W1, float* __restrict__ b1,
                         float* __restrict__ W2, float* __restrict__ b2,
                         __bf16* __restrict__ Wt)
{
    int i = blockIdx.x * 256 + threadIdx.x;
    if (i < 107 * 432) {
        int k = i / 432, c = i % 432;
        int q = c / 108, cc = c - q * 108;
        float v = 0.f;
        if (cc < 107) {
            if (q == 0)      v = l1a[k * 107 + cc];
            else if (q == 1) v = l1a[(207 + k) * 107 + cc];
            else if (q == 2) v = l1b[k * 107 + cc];
            else             v = l1b[(207 + k) * 107 + cc];
        }
        W1[i] = v;
    }
    if (i < 432) {
        int q = i / 108, cc = i - q * 108;
        b1[i] = (cc < 107) ? (q == 0 ? l1ab[cc] : (q == 3 ? l1bb[cc] : 0.f)) : 0.f;
    }
    if (i < 100 * 416) {
        int k = i / 416, c = i % 416;
        int q = c / 104, cc = c - q * 104;
        float v = 0.f;
        if (cc < 100) {
            if (q == 0)      v = l2a[k * 100 + cc];
            else if (q == 1) v = l2a[(200 + k) * 100 + cc];
            else if (q == 2) v = l2b[k * 100 + cc];
            else             v = l2b[(200 + k) * 100 + cc];
        }
        W2[i] = v;
    }
    if (i < 416) {
        int q = i / 104, cc = i - q * 104;
        b2[i] = (cc < 100) ? (q == 0 ? l2ab[cc] : (q == 3 ? l2bb[cc] : 0.f)) : 0.f;
    }
    // Wt[q][col][k]: transposed bf16 mid blocks (k>=100 or col>=ND -> 0)
    if (i < 4 * 128 * 128) {
        int q = i >> 14, col = (i >> 7) & 127, k = i & 127;
        const float* Wm = (q == 0) ? l1a + 107 * 107 :
                          (q == 1) ? l1b + 107 * 107 :
                          (q == 2) ? l2a + 100 * 100 : l2b + 100 * 100;
        int ND = (q < 2) ? 107 : 100;
        float v = (k < 100 && col < ND) ? Wm[k * ND + col] : 0.f;
        Wt[i] = (__bf16)v;
    }
}

extern "C" void kernel_launch(void* const* d_in, const int* in_sizes, int n_in,
                              void* d_out, int out_size, void* d_ws, size_t ws_size,
                              hipStream_t stream)
{
    const float* x    = (const float*)d_in[0];
    const int*   eidx = (const int*)d_in[1];
    const float* eatt = (const float*)d_in[2];
    const float* l1aw = (const float*)d_in[3];
    const float* l1ab = (const float*)d_in[4];
    const float* l1bw = (const float*)d_in[5];
    const float* l1bb = (const float*)d_in[6];
    const float* m1w1 = (const float*)d_in[7];
    const float* m1b1 = (const float*)d_in[8];
    const float* m1w2 = (const float*)d_in[9];
    const float* m1b2 = (const float*)d_in[10];
    const float* l2aw = (const float*)d_in[11];
    const float* l2ab = (const float*)d_in[12];
    const float* l2bw = (const float*)d_in[13];
    const float* l2bb = (const float*)d_in[14];
    const float* m2w1 = (const float*)d_in[15];
    const float* m2b1 = (const float*)d_in[16];
    const float* m2w2 = (const float*)d_in[17];
    const float* m2b2 = (const float*)d_in[18];
    float* out = (float*)d_out;

    // workspace layout (4-byte units), ~322 MB
    float*  ws   = (float*)d_ws;
    __bf16* NTbf = (__bf16*)ws;                         // 50000*432 bf16 = 43.2 MB
    float*  bufA = ws + 10800000;                       // 50000*112 fp32
    float*  bufC = bufA + 5600000;                      // 50000*100 fp32 (h)
    float*  W1   = bufC + 5000000;                      // 46,224
    float*  b1v  = W1 + 46224;                          // 432
    float*  W2   = b1v + 432;                           // 41,600
    float*  b2v  = W2 + 41600;                          // 416
    __bf16* Wt   = (__bf16*)(b2v + 416);                // 4*128*128 bf16
    int*    off  = (int*)(Wt + 65536);                  // 100,000
    int*    cur  = off + NN2;                           // 100,000
    int*    bsum = cur + NN2;                           // 512
    int*    srcp = bsum + 512;                          // 800,000
    int*    eord = srcp + NE;                           // 800,000
    __bf16* ebf  = (__bf16*)(eord + NE);                // (NE+128)*128 bf16
    float*  bufB = (float*)(ebf + (size_t)(NE + 128) * 128);  // 5,000,000 fp32

    const int* dst = eidx + NE;

    assemble<<<256, 256, 0, stream>>>(l1aw, l1ab, l1bw, l1bb, l2aw, l2ab, l2bw, l2bb,
                                      W1, b1v, W2, b2v, Wt);

    // ---- CSR build (dst-sorted, per half; emits srcp/eord) ----
    zero_ints<<<(NN2 + 255) / 256, 256, 0, stream>>>(cur, NN2);
    count_edges<<<(NE + 255) / 256, 256, 0, stream>>>(dst, cur);
    scan_blocks<<<(NN2 + 255) / 256, 256, 0, stream>>>(cur, off, bsum, NN2);
    scan_bsum<<<1, 512, 0, stream>>>(bsum, (NN2 + 255) / 256);
    scan_add<<<(NN2 + 255) / 256, 256, 0, stream>>>(off, bsum, cur, NN2);
    scatter_edges<<<(NE + 255) / 256, 256, 0, stream>>>(eidx, cur, srcp, eord);

    // ---- eattr gather -> CSR-ordered bf16[128] ----
    cvt_gather<<<NE * 16 / 256, 256, 0, stream>>>(eatt, eord, ebf);

    const int CG = (NN + GNODES - 1) / GNODES;   // 1137 blocks

    // ---- conv1 ----
    mm_bf16<107, true><<<dim3(98, 7), 256, 0, stream>>>(x, W1, b1v, NTbf,
                                                        107, NN, 432, 432, 4, 0);
    conv_fused<107, 432><<<CG, 256, 0, stream>>>(ebf, Wt, srcp, off, NTbf, x, bufA,
                                                 0, 108, 324, 216);
    mm_bf16<112, false><<<dim3(98, 2), 256, 0, stream>>>(bufA, m1w1, m1b1, bufB,
                                                         107, NN, 100, 100, 4, 1);
    mm_bf16<100, false><<<dim3(98, 2), 256, 0, stream>>>(bufB, m1w2, m1b2, bufC,
                                                         100, NN, 100, 100, 4, 1);

    // ---- conv2 ----  (h in bufC)
    mm_bf16<100, true><<<dim3(98, 7), 256, 0, stream>>>(bufC, W2, b2v, NTbf,
                                                        100, NN, 416, 416, 4, 0);
    conv_fused<100, 416><<<CG, 256, 0, stream>>>(ebf, Wt + 2 * 16384, srcp, off,
                                                 NTbf, bufC, bufA,
                                                 0, 104, 312, 208);
    mm_bf16<112, false><<<dim3(98, 1), 256, 0, stream>>>(bufA, m2w1, m2b1, bufB,
                                                         100, NN, 64, 64, 4, 1);
    mm_bf16<64, false><<<dim3(98, 2), 256, 0, stream>>>(bufB, m2w2, m2b2, out,
                                                        64, NN, 100, 100, 4, 0);
}

// Round 15
// 1086.828 us; speedup vs baseline: 2.1420x; 2.1420x over previous
//
#include <hip/hip_runtime.h>

// RuleGraphNet: 2x TripleConv(+mlp), N=50000 nodes, E=800000 edges.
// R13 pipeline: eattr gathered to CSR-ordered bf16[NE][128]; all 4 edge
// mid-GEMMs in one dispatch (mt_all, barrier-free wave-private copy-out);
// MT1/MT2 CSR-ordered -> sequential aggregation reads; NT bf16; aggregation
// wave owns 1 dst node, lane owns a column pair, register accumulation over
// both phases; self fused.

#define NN 50000
#define NE 800000
#define EHALF 400000
#define NN2 100000
#define GB 8            // edges batched per gather group

typedef __attribute__((ext_vector_type(4))) float  f32x4;
typedef __attribute__((ext_vector_type(8))) __bf16 bf16x8;
typedef __attribute__((ext_vector_type(4))) __bf16 bf16x4;

__device__ __forceinline__ float bf16lo(unsigned u) {
    union { unsigned u; float f; } c; c.u = u << 16; return c.f;
}
__device__ __forceinline__ float bf16hi(unsigned u) {
    union { unsigned u; float f; } c; c.u = u & 0xffff0000u; return c.f;
}

// ---------------- generic bf16 MFMA GEMM (LDS-staged A, fp32 in) ----------
template<int K, bool OBF16>
__global__ __launch_bounds__(256)
void mm_bf16(const float* __restrict__ A, const float* __restrict__ W,
             const float* __restrict__ bias, void* __restrict__ Outp,
             int Kw, int M, int N, int ldo, int RT, int relu)
{
    __shared__ __align__(16) __bf16 et[128 * 128];
    const int t = threadIdx.x;
    const int lane = t & 63, w = t >> 6;
    const int mh = w & 1, nh = w >> 1;
    const int l15 = lane & 15, l4 = lane >> 4;
    const int cb = blockIdx.y * 64;

    bf16x8 wf[2][4];
    const int colbase = cb + nh * 32 + l15;
    #pragma unroll
    for (int nt = 0; nt < 2; ++nt) {
        int col = colbase + nt * 16;
        #pragma unroll
        for (int ks = 0; ks < 4; ++ks) {
            bf16x8 f;
            #pragma unroll
            for (int j = 0; j < 8; ++j) {
                int k = ks * 32 + l4 * 8 + j;
                float v = (k < Kw && col < N) ? W[k * N + col] : 0.f;
                f[j] = (__bf16)v;
            }
            wf[nt][ks] = f;
        }
    }
    float bv[2] = {0.f, 0.f};
    if (bias) {
        #pragma unroll
        for (int nt = 0; nt < 2; ++nt) {
            int col = colbase + nt * 16;
            if (col < N) bv[nt] = bias[col];
        }
    }

    for (int it = 0; it < RT; ++it) {
        const int row0 = (blockIdx.x * RT + it) * 128;
        if (row0 >= M) break;
        __syncthreads();
        if constexpr (K % 4 == 0) {
            constexpr int QK = K / 4;
            for (int i = t; i < 128 * QK; i += 256) {
                int row = i / QK, q = i - row * QK;
                int gr = row0 + row;
                float4 v = {0.f, 0.f, 0.f, 0.f};
                if (gr < M) v = *(const float4*)(A + (size_t)gr * K + q * 4);
                bf16x4 b;
                b[0] = (__bf16)v.x; b[1] = (__bf16)v.y;
                b[2] = (__bf16)v.z; b[3] = (__bf16)v.w;
                *(bf16x4*)(et + row * 128 + ((q * 4) ^ ((row & 7) << 3))) = b;
            }
            constexpr int QP = (128 - K) / 4;
            if constexpr (QP > 0) {
                for (int i = t; i < 128 * QP; i += 256) {
                    int row = i / QP, q = QK + (i - (i / QP) * QP);
                    bf16x4 z;
                    z[0] = (__bf16)0.f; z[1] = (__bf16)0.f;
                    z[2] = (__bf16)0.f; z[3] = (__bf16)0.f;
                    *(bf16x4*)(et + row * 128 + ((q * 4) ^ ((row & 7) << 3))) = z;
                }
            }
        } else {
            for (int i = t; i < 128 * 128; i += 256) {
                int row = i >> 7, k = i & 127;
                int gr = row0 + row;
                float v = (k < K && gr < M) ? A[(size_t)gr * K + k] : 0.f;
                et[row * 128 + (k ^ ((row & 7) << 3))] = (__bf16)v;
            }
        }
        __syncthreads();

        f32x4 c[4][2] = {};
        #pragma unroll
        for (int ks = 0; ks < 4; ++ks) {
            #pragma unroll
            for (int mt = 0; mt < 4; ++mt) {
                int arow = mh * 64 + mt * 16 + l15;
                bf16x8 a = *(const bf16x8*)(et + arow * 128 +
                                            ((ks * 32 + l4 * 8) ^ ((l15 & 7) << 3)));
                c[mt][0] = __builtin_amdgcn_mfma_f32_16x16x32_bf16(a, wf[0][ks], c[mt][0], 0, 0, 0);
                c[mt][1] = __builtin_amdgcn_mfma_f32_16x16x32_bf16(a, wf[1][ks], c[mt][1], 0, 0, 0);
            }
        }

        #pragma unroll
        for (int mt = 0; mt < 4; ++mt) {
            #pragma unroll
            for (int nt = 0; nt < 2; ++nt) {
                int col = colbase + nt * 16;
                #pragma unroll
                for (int r = 0; r < 4; ++r) {
                    int row = row0 + mh * 64 + mt * 16 + l4 * 4 + r;
                    if constexpr (OBF16) {
                        if (row < M && col < ldo)
                            ((__bf16*)Outp)[(size_t)row * ldo + col] =
                                (__bf16)(c[mt][nt][r] + bv[nt]);
                    } else {
                        if (row < M && col < N) {
                            float v = c[mt][nt][r] + bv[nt];
                            if (relu) v = fmaxf(v, 0.f);
                            ((float*)Outp)[(size_t)row * ldo + col] = v;
                        }
                    }
                }
            }
        }
    }
}

// ---------------- CSR build (edges sorted by dst, per half) ----------------
__global__ void zero_ints(int* __restrict__ p, int n)
{
    int i = blockIdx.x * 256 + threadIdx.x;
    if (i < n) p[i] = 0;
}

__global__ void count_edges(const int* __restrict__ dst, int* __restrict__ cnt)
{
    int e = blockIdx.x * 256 + threadIdx.x;
    if (e < NE) atomicAdd(&cnt[dst[e] + (e >= EHALF ? NN : 0)], 1);
}

__global__ void scan_blocks(const int* __restrict__ cnt, int* __restrict__ off,
                            int* __restrict__ bsum, int n)
{
    __shared__ int s[256];
    int t = threadIdx.x, g = blockIdx.x * 256 + t;
    int v = (g < n) ? cnt[g] : 0;
    s[t] = v; __syncthreads();
    for (int d = 1; d < 256; d <<= 1) {
        int add = (t >= d) ? s[t - d] : 0;
        __syncthreads();
        s[t] += add;
        __syncthreads();
    }
    if (g < n) off[g] = s[t] - v;
    if (t == 255) bsum[blockIdx.x] = s[255];
}

__global__ void scan_bsum(int* __restrict__ bsum, int nb)
{
    __shared__ int s[512];
    int t = threadIdx.x;
    int v = (t < nb) ? bsum[t] : 0;
    s[t] = v; __syncthreads();
    for (int d = 1; d < 512; d <<= 1) {
        int add = (t >= d) ? s[t - d] : 0;
        __syncthreads();
        s[t] += add;
        __syncthreads();
    }
    if (t < nb) bsum[t] = s[t] - v;
}

__global__ void scan_add(int* __restrict__ off, const int* __restrict__ bsum,
                         int* __restrict__ cur, int n)
{
    int g = blockIdx.x * 256 + threadIdx.x;
    if (g < n) { int o = off[g] + bsum[blockIdx.x]; off[g] = o; cur[g] = o; }
}

__global__ void scatter_edges(const int* __restrict__ eidx, int* __restrict__ cur,
                              int* __restrict__ srcp, int* __restrict__ eord)
{
    int e = blockIdx.x * 256 + threadIdx.x;
    if (e < NE) {
        int s = eidx[e], d = eidx[NE + e];
        int pos = atomicAdd(&cur[d + (e >= EHALF ? NN : 0)], 1);
        srcp[pos] = s;
        eord[pos] = e;
    }
}

// ------- eattr gather -> CSR-ordered bf16 [NE][128] (zero-padded) ---------
__global__ __launch_bounds__(256)
void cvt_gather(const float* __restrict__ eatt, const int* __restrict__ eord,
                __bf16* __restrict__ ebf)
{
    int i = blockIdx.x * 256 + threadIdx.x;     // NE*16 threads, 8 cols each
    int row = i >> 4, oct = i & 15;
    if (row >= NE) return;
    const float* p = eatt + (size_t)eord[row] * 100;
    bf16x8 o;
    if (oct < 12) {
        float4 v0 = *(const float4*)(p + oct * 8);
        float4 v1 = *(const float4*)(p + oct * 8 + 4);
        o[0] = (__bf16)v0.x; o[1] = (__bf16)v0.y; o[2] = (__bf16)v0.z; o[3] = (__bf16)v0.w;
        o[4] = (__bf16)v1.x; o[5] = (__bf16)v1.y; o[6] = (__bf16)v1.z; o[7] = (__bf16)v1.w;
    } else if (oct == 12) {
        float4 v0 = *(const float4*)(p + 96);
        o[0] = (__bf16)v0.x; o[1] = (__bf16)v0.y; o[2] = (__bf16)v0.z; o[3] = (__bf16)v0.w;
        o[4] = (__bf16)0.f; o[5] = (__bf16)0.f; o[6] = (__bf16)0.f; o[7] = (__bf16)0.f;
    } else {
        #pragma unroll
        for (int j = 0; j < 8; ++j) o[j] = (__bf16)0.f;
    }
    *(bf16x8*)(ebf + (size_t)row * 128 + oct * 8) = o;
}

// ---------------- mt_all: all 4 edge mid-GEMMs in one dispatch ------------
// grid 12500: quarter q = bid/3125 (0: MT1 half-a, 1: MT1 half-b, 2: MT2
// half-a, 3: MT2 half-b); 128 rows per block. W fragments from pre-transposed
// Wt[q][col][k] bf16 (16 vector loads). Input LDS-free; C staged in LDS
// (stride 116, conflict-free). Copy-out is WAVE-PRIVATE (wave (mh,nq) wrote
// exactly rows [mh*64,+64) x cols [nq*64,+64) of ct) -> NO barrier.
__global__ __launch_bounds__(256)
void mt_all(const __bf16* __restrict__ ebf,    // [NE][128] CSR order
            const __bf16* __restrict__ Wt,     // [4][128][128]
            __bf16* __restrict__ MT1,          // [NE][112] CSR order
            __bf16* __restrict__ MT2)          // [NE][112] CSR order
{
    __shared__ __align__(16) __bf16 ct[128 * 116];   // 29.7 KB
    const int t = threadIdx.x;
    const int lane = t & 63, w = t >> 6;
    const int mh = w & 1, nq = w >> 1;
    const int l15 = lane & 15, l4 = lane >> 4;
    const int q = blockIdx.x / 3125;
    const int tile = blockIdx.x - q * 3125;
    const size_t row0 = (size_t)tile * 128 + (size_t)(q & 1) * EHALF;
    __bf16* MT = (q < 2) ? MT1 : MT2;
    const __bf16* Wq = Wt + (size_t)q * 16384;

    // W fragments: 16 x 16B vector loads from transposed table
    bf16x8 wf[4][4];
    const int colbase = nq * 64 + l15;
    #pragma unroll
    for (int nt = 0; nt < 4; ++nt) {
        #pragma unroll
        for (int ks = 0; ks < 4; ++ks)
            wf[nt][ks] = *(const bf16x8*)(Wq + (colbase + nt * 16) * 128 +
                                          ks * 32 + l4 * 8);
    }

    f32x4 c[4][4] = {};
    #pragma unroll
    for (int ks = 0; ks < 4; ++ks) {
        #pragma unroll
        for (int mt = 0; mt < 4; ++mt) {
            size_t row = row0 + mh * 64 + mt * 16 + l15;
            bf16x8 a = *(const bf16x8*)(ebf + row * 128 + ks * 32 + l4 * 8);
            #pragma unroll
            for (int nt = 0; nt < 4; ++nt)
                c[mt][nt] = __builtin_amdgcn_mfma_f32_16x16x32_bf16(
                    a, wf[nt][ks], c[mt][nt], 0, 0, 0);
        }
    }
    #pragma unroll
    for (int mt = 0; mt < 4; ++mt) {
        #pragma unroll
        for (int nt = 0; nt < 4; ++nt) {
            int col = colbase + nt * 16;
            if (col < 112) {
                #pragma unroll
                for (int r = 0; r < 4; ++r) {
                    int lrow = mh * 64 + mt * 16 + l4 * 4 + r;
                    ct[lrow * 116 + col] = (__bf16)c[mt][nt][r];
                }
            }
        }
    }
    // wave-private copy-out (no barrier): rows [mh*64,+64), cols nq? 64..111 : 0..63
    const int rbase = mh * 64;
    __bf16* gout = MT + (row0 + rbase) * 112;
    if (nq == 0) {
        #pragma unroll
        for (int k = 0; k < 16; ++k) {
            int i = lane + 64 * k;
            int row = i >> 4, ch = i & 15;
            *(uint2*)(gout + row * 112 + ch * 4) =
                *(const uint2*)(ct + (rbase + row) * 116 + ch * 4);
        }
    } else {
        #pragma unroll
        for (int k = 0; k < 12; ++k) {
            int i = lane + 64 * k;
            int row = i / 12, ch = i - row * 12;
            *(uint2*)(gout + row * 112 + 64 + ch * 4) =
                *(const uint2*)(ct + (rbase + row) * 116 + 64 + ch * 4);
        }
    }
}

// ---------------- edge_aggr3: both phases, register accumulation ----------
// MT is CSR-ordered: row index == CSR position (no indirection). Wave owns
// ONE dst node; lane owns column pair (2*lane, 2*lane+1). Per edge: one u32
// MT load (sequential rows) + one u32 NT[src] load. NT[dst] once per phase.
// Output stride 112, pad cols zeroed.
template<int ND, int NTS>
__global__ __launch_bounds__(256)
void edge_aggr3(const __bf16* __restrict__ MT,    // [NE][112] CSR order
                const int* __restrict__ srcp,     // [NE] src per CSR position
                const int* __restrict__ off,      // [NN2]
                const __bf16* __restrict__ NT,    // [NN][NTS] bf16
                const float* __restrict__ self,   // [NN][ND] fp32
                float* __restrict__ aggr,         // [NN][112]
                int blkd0, int blks0, int blkd1, int blks1)
{
    const int t = threadIdx.x;
    const int lane = t & 63, wv = t >> 6;
    const int c0 = lane * 2;
    const bool a0 = c0 < ND, a1 = c0 + 1 < ND;
    const int n = blockIdx.x * 4 + wv;     // one node per wave

    float acc0 = 0.f, acc1 = 0.f;

    #pragma unroll
    for (int phase = 0; phase < 2; ++phase) {
        const int blkd = phase ? blkd1 : blkd0;
        const int blks = phase ? blks1 : blks0;
        const int idx = phase * NN + n;
        const int pb = off[idx];
        const int pe = (idx + 1 == NN2) ? NE : off[idx + 1];

        float nd0 = 0.f, nd1 = 0.f;
        if (a0) {
            unsigned nd = *(const unsigned*)(NT + (size_t)n * NTS + blkd + c0);
            nd0 = bf16lo(nd); nd1 = bf16hi(nd);
        }

        for (int p = pb; p < pe; p += GB) {
            int ok[GB], ss[GB];
            #pragma unroll
            for (int i = 0; i < GB; ++i) {
                int pp = p + i;
                ok[i] = pp < pe;
                ss[i] = ok[i] ? srcp[pp] : 0;
            }
            unsigned mtw[GB], nsw[GB];
            #pragma unroll
            for (int i = 0; i < GB; ++i) {
                mtw[i] = 0u; nsw[i] = 0u;
                if (ok[i] && a0) {
                    mtw[i] = *(const unsigned*)(MT + (size_t)(p + i) * 112 + c0);
                    nsw[i] = *(const unsigned*)(NT + (size_t)ss[i] * NTS + blks + c0);
                }
            }
            #pragma unroll
            for (int i = 0; i < GB; ++i) {
                if (!ok[i]) continue;             // wave-uniform
                acc0 += fmaxf(bf16lo(mtw[i]) + nd0 + bf16lo(nsw[i]), 0.f);
                acc1 += fmaxf(bf16hi(mtw[i]) + nd1 + bf16hi(nsw[i]), 0.f);
            }
        }
    }

    if (c0 < 112) {
        const size_t g0 = (size_t)n * 112 + c0;
        aggr[g0]     = a0 ? (acc0 + self[(size_t)n * ND + c0])     : 0.f;
        aggr[g0 + 1] = a1 ? (acc1 + self[(size_t)n * ND + c0 + 1]) : 0.f;
    }
}

// ---- weight assembly: padded concat blocks + transposed mid blocks -------
__global__ void assemble(const float* __restrict__ l1a, const float* __restrict__ l1ab,
                         const float* __restrict__ l1b, const float* __restrict__ l1bb,
                         const float* __restrict__ l2a, const float* __restrict__ l2ab,
                         const float* __restrict__ l2b, const float* __restrict__ l2bb,
                         float* __restrict__ W1, float* __restrict__ b1,
                         float* __restrict__ W2, float* __restrict__ b2,
                         __bf16* __restrict__ Wt)
{
    int i = blockIdx.x * 256 + threadIdx.x;
    if (i < 107 * 432) {
        int k = i / 432, c = i % 432;
        int q = c / 108, cc = c - q * 108;
        float v = 0.f;
        if (cc < 107) {
            if (q == 0)      v = l1a[k * 107 + cc];
            else if (q == 1) v = l1a[(207 + k) * 107 + cc];
            else if (q == 2) v = l1b[k * 107 + cc];
            else             v = l1b[(207 + k) * 107 + cc];
        }
        W1[i] = v;
    }
    if (i < 432) {
        int q = i / 108, cc = i - q * 108;
        b1[i] = (cc < 107) ? (q == 0 ? l1ab[cc] : (q == 3 ? l1bb[cc] : 0.f)) : 0.f;
    }
    if (i < 100 * 416) {
        int k = i / 416, c = i % 416;
        int q = c / 104, cc = c - q * 104;
        float v = 0.f;
        if (cc < 100) {
            if (q == 0)      v = l2a[k * 100 + cc];
            else if (q == 1) v = l2a[(200 + k) * 100 + cc];
            else if (q == 2) v = l2b[k * 100 + cc];
            else             v = l2b[(200 + k) * 100 + cc];
        }
        W2[i] = v;
    }
    if (i < 416) {
        int q = i / 104, cc = i - q * 104;
        b2[i] = (cc < 100) ? (q == 0 ? l2ab[cc] : (q == 3 ? l2bb[cc] : 0.f)) : 0.f;
    }
    // Wt[q][col][k]: transposed bf16 mid blocks (k>=100 or col>=ND -> 0)
    if (i < 4 * 128 * 128) {
        int q = i >> 14, col = (i >> 7) & 127, k = i & 127;
        const float* Wm = (q == 0) ? l1a + 107 * 107 :
                          (q == 1) ? l1b + 107 * 107 :
                          (q == 2) ? l2a + 100 * 100 : l2b + 100 * 100;
        int ND = (q < 2) ? 107 : 100;
        float v = (k < 100 && col < ND) ? Wm[k * ND + col] : 0.f;
        Wt[i] = (__bf16)v;
    }
}

extern "C" void kernel_launch(void* const* d_in, const int* in_sizes, int n_in,
                              void* d_out, int out_size, void* d_ws, size_t ws_size,
                              hipStream_t stream)
{
    const float* x    = (const float*)d_in[0];
    const int*   eidx = (const int*)d_in[1];
    const float* eatt = (const float*)d_in[2];
    const float* l1aw = (const float*)d_in[3];
    const float* l1ab = (const float*)d_in[4];
    const float* l1bw = (const float*)d_in[5];
    const float* l1bb = (const float*)d_in[6];
    const float* m1w1 = (const float*)d_in[7];
    const float* m1b1 = (const float*)d_in[8];
    const float* m1w2 = (const float*)d_in[9];
    const float* m1b2 = (const float*)d_in[10];
    const float* l2aw = (const float*)d_in[11];
    const float* l2ab = (const float*)d_in[12];
    const float* l2bw = (const float*)d_in[13];
    const float* l2bb = (const float*)d_in[14];
    const float* m2w1 = (const float*)d_in[15];
    const float* m2b1 = (const float*)d_in[16];
    const float* m2w2 = (const float*)d_in[17];
    const float* m2b2 = (const float*)d_in[18];
    float* out = (float*)d_out;

    // workspace layout (4-byte units), ~657 MB
    float*  ws   = (float*)d_ws;
    __bf16* NTbf = (__bf16*)ws;                         // 50000*432 bf16 = 43.2 MB
    float*  bufA = ws + 10800000;                       // 50000*112 fp32
    float*  bufC = bufA + 5600000;                      // 50000*100 fp32 (h)
    float*  W1   = bufC + 5000000;                      // 46,224
    float*  b1v  = W1 + 46224;                          // 432
    float*  W2   = b1v + 432;                           // 41,600
    float*  b2v  = W2 + 41600;                          // 416
    __bf16* Wt   = (__bf16*)(b2v + 416);                // 4*128*128 bf16 = 32768 f
    int*    off  = (int*)(Wt + 65536);                  // 100,000
    int*    cur  = off + NN2;                           // 100,000
    int*    bsum = cur + NN2;                           // 512
    int*    srcp = bsum + 512;                          // 800,000
    int*    eord = srcp + NE;                           // 800,000
    __bf16* ebf  = (__bf16*)(eord + NE);                // NE*128 bf16 = 204.8 MB
    __bf16* MT1  = ebf + (size_t)NE * 128;              // NE*112 bf16 = 179.2 MB
    __bf16* MT2  = MT1 + (size_t)NE * 112;              // NE*112 bf16 = 179.2 MB
    float*  bufB = (float*)MT1;                         // t1/t2 alias (MT1 consumed)

    const int* dst = eidx + NE;

    assemble<<<256, 256, 0, stream>>>(l1aw, l1ab, l1bw, l1bb, l2aw, l2ab, l2bw, l2bb,
                                      W1, b1v, W2, b2v, Wt);

    // ---- CSR build (dst-sorted, per half; emits srcp/eord) ----
    zero_ints<<<(NN2 + 255) / 256, 256, 0, stream>>>(cur, NN2);
    count_edges<<<(NE + 255) / 256, 256, 0, stream>>>(dst, cur);
    scan_blocks<<<(NN2 + 255) / 256, 256, 0, stream>>>(cur, off, bsum, NN2);
    scan_bsum<<<1, 512, 0, stream>>>(bsum, (NN2 + 255) / 256);
    scan_add<<<(NN2 + 255) / 256, 256, 0, stream>>>(off, bsum, cur, NN2);
    scatter_edges<<<(NE + 255) / 256, 256, 0, stream>>>(eidx, cur, srcp, eord);

    // ---- eattr gather -> CSR-ordered bf16[128] ----
    cvt_gather<<<NE * 16 / 256, 256, 0, stream>>>(eatt, eord, ebf);

    // ---- all 4 edge mid-GEMMs in one dispatch ----
    mt_all<<<12500, 256, 0, stream>>>(ebf, Wt, MT1, MT2);

    const int AG = NN / 4;   // 12500 blocks: 4 waves x 1 node each

    // ---- conv1 ----
    mm_bf16<107, true><<<dim3(98, 7), 256, 0, stream>>>(x, W1, b1v, NTbf,
                                                        107, NN, 432, 432, 4, 0);
    edge_aggr3<107, 432><<<AG, 256, 0, stream>>>(MT1, srcp, off, NTbf, x, bufA,
                                                 0, 108, 324, 216);
    mm_bf16<112, false><<<dim3(98, 2), 256, 0, stream>>>(bufA, m1w1, m1b1, bufB,
                                                         107, NN, 100, 100, 4, 1);
    mm_bf16<100, false><<<dim3(98, 2), 256, 0, stream>>>(bufB, m1w2, m1b2, bufC,
                                                         100, NN, 100, 100, 4, 1);

    // ---- conv2 ----  (h in bufC)
    mm_bf16<100, true><<<dim3(98, 7), 256, 0, stream>>>(bufC, W2, b2v, NTbf,
                                                        100, NN, 416, 416, 4, 0);
    edge_aggr3<100, 416><<<AG, 256, 0, stream>>>(MT2, srcp, off, NTbf, bufC, bufA,
                                                 0, 104, 312, 208);
    mm_bf16<112, false><<<dim3(98, 1), 256, 0, stream>>>(bufA, m2w1, m2b1, bufB,
                                                         100, NN, 64, 64, 4, 1);
    mm_bf16<64, false><<<dim3(98, 2), 256, 0, stream>>>(bufB, m2w2, m2b2, out,
                                                        64, NN, 100, 100, 4, 0);
}

// Round 16
// 1018.192 us; speedup vs baseline: 2.2864x; 1.0674x over previous
//
#include <hip/hip_runtime.h>

// RuleGraphNet: 2x TripleConv(+mlp), N=50000 nodes, E=800000 edges.
// Pipeline: eattr gathered to CSR-ordered bf16[NE][128]; all 4 edge mid-GEMMs
// in one dispatch (mt_all, 64-row tiles, wave-private copy-out, no barriers);
// MT1/MT2 CSR-ordered -> sequential aggregation; NT bf16; aggregation wave
// owns 1 dst node, lane owns a column pair, register accumulation over both
// phases, self fused. ALL dense GEMMs use pre-transposed bf16 weight tables
// (vector-load fragment setup; no scalar W prologue).

#define NN 50000
#define NE 800000
#define EHALF 400000
#define NN2 100000
#define GB 8            // edges batched per gather group

typedef __attribute__((ext_vector_type(4))) float  f32x4;
typedef __attribute__((ext_vector_type(8))) __bf16 bf16x8;
typedef __attribute__((ext_vector_type(4))) __bf16 bf16x4;

__device__ __forceinline__ float bf16lo(unsigned u) {
    union { unsigned u; float f; } c; c.u = u << 16; return c.f;
}
__device__ __forceinline__ float bf16hi(unsigned u) {
    union { unsigned u; float f; } c; c.u = u & 0xffff0000u; return c.f;
}

// ------- generic bf16 MFMA GEMM, W from pre-transposed bf16 table ---------
// Out[M][ldo] = act(A[M][K] @ W + bias); Wtt[colPad][128] bf16 (zero-padded).
template<int K, bool OBF16>
__global__ __launch_bounds__(256)
void mm_bf16t(const float* __restrict__ A, const __bf16* __restrict__ Wtt,
              const float* __restrict__ bias, void* __restrict__ Outp,
              int M, int N, int ldo, int RT, int relu)
{
    __shared__ __align__(16) __bf16 et[128 * 128];
    const int t = threadIdx.x;
    const int lane = t & 63, w = t >> 6;
    const int mh = w & 1, nh = w >> 1;
    const int l15 = lane & 15, l4 = lane >> 4;
    const int cb = blockIdx.y * 64;

    bf16x8 wf[2][4];
    const int colbase = cb + nh * 32 + l15;
    #pragma unroll
    for (int nt = 0; nt < 2; ++nt)
        #pragma unroll
        for (int ks = 0; ks < 4; ++ks)
            wf[nt][ks] = *(const bf16x8*)(Wtt + (colbase + nt * 16) * 128 +
                                          ks * 32 + l4 * 8);
    float bv[2] = {0.f, 0.f};
    if (bias) {
        #pragma unroll
        for (int nt = 0; nt < 2; ++nt) {
            int col = colbase + nt * 16;
            if (col < N) bv[nt] = bias[col];
        }
    }

    for (int it = 0; it < RT; ++it) {
        const int row0 = (blockIdx.x * RT + it) * 128;
        if (row0 >= M) break;
        __syncthreads();
        if constexpr (K % 4 == 0) {
            constexpr int QK = K / 4;
            for (int i = t; i < 128 * QK; i += 256) {
                int row = i / QK, q = i - row * QK;
                int gr = row0 + row;
                float4 v = {0.f, 0.f, 0.f, 0.f};
                if (gr < M) v = *(const float4*)(A + (size_t)gr * K + q * 4);
                bf16x4 b;
                b[0] = (__bf16)v.x; b[1] = (__bf16)v.y;
                b[2] = (__bf16)v.z; b[3] = (__bf16)v.w;
                *(bf16x4*)(et + row * 128 + ((q * 4) ^ ((row & 7) << 3))) = b;
            }
            constexpr int QP = (128 - K) / 4;
            if constexpr (QP > 0) {
                for (int i = t; i < 128 * QP; i += 256) {
                    int row = i / QP, q = QK + (i - (i / QP) * QP);
                    bf16x4 z;
                    z[0] = (__bf16)0.f; z[1] = (__bf16)0.f;
                    z[2] = (__bf16)0.f; z[3] = (__bf16)0.f;
                    *(bf16x4*)(et + row * 128 + ((q * 4) ^ ((row & 7) << 3))) = z;
                }
            }
        } else {
            for (int i = t; i < 128 * 128; i += 256) {
                int row = i >> 7, k = i & 127;
                int gr = row0 + row;
                float v = (k < K && gr < M) ? A[(size_t)gr * K + k] : 0.f;
                et[row * 128 + (k ^ ((row & 7) << 3))] = (__bf16)v;
            }
        }
        __syncthreads();

        f32x4 c[4][2] = {};
        #pragma unroll
        for (int ks = 0; ks < 4; ++ks) {
            #pragma unroll
            for (int mt = 0; mt < 4; ++mt) {
                int arow = mh * 64 + mt * 16 + l15;
                bf16x8 a = *(const bf16x8*)(et + arow * 128 +
                                            ((ks * 32 + l4 * 8) ^ ((l15 & 7) << 3)));
                c[mt][0] = __builtin_amdgcn_mfma_f32_16x16x32_bf16(a, wf[0][ks], c[mt][0], 0, 0, 0);
                c[mt][1] = __builtin_amdgcn_mfma_f32_16x16x32_bf16(a, wf[1][ks], c[mt][1], 0, 0, 0);
            }
        }

        #pragma unroll
        for (int mt = 0; mt < 4; ++mt) {
            #pragma unroll
            for (int nt = 0; nt < 2; ++nt) {
                int col = colbase + nt * 16;
                #pragma unroll
                for (int r = 0; r < 4; ++r) {
                    int row = row0 + mh * 64 + mt * 16 + l4 * 4 + r;
                    if constexpr (OBF16) {
                        if (row < M && col < ldo)
                            ((__bf16*)Outp)[(size_t)row * ldo + col] =
                                (__bf16)(c[mt][nt][r] + bv[nt]);
                    } else {
                        if (row < M && col < N) {
                            float v = c[mt][nt][r] + bv[nt];
                            if (relu) v = fmaxf(v, 0.f);
                            ((float*)Outp)[(size_t)row * ldo + col] = v;
                        }
                    }
                }
            }
        }
    }
}

// ---------------- CSR build (edges sorted by dst, per half) ----------------
__global__ void zero_ints(int* __restrict__ p, int n)
{
    int i = blockIdx.x * 256 + threadIdx.x;
    if (i < n) p[i] = 0;
}

__global__ void count_edges(const int* __restrict__ dst, int* __restrict__ cnt)
{
    int e = blockIdx.x * 256 + threadIdx.x;
    if (e < NE) atomicAdd(&cnt[dst[e] + (e >= EHALF ? NN : 0)], 1);
}

__global__ void scan_blocks(const int* __restrict__ cnt, int* __restrict__ off,
                            int* __restrict__ bsum, int n)
{
    __shared__ int s[256];
    int t = threadIdx.x, g = blockIdx.x * 256 + t;
    int v = (g < n) ? cnt[g] : 0;
    s[t] = v; __syncthreads();
    for (int d = 1; d < 256; d <<= 1) {
        int add = (t >= d) ? s[t - d] : 0;
        __syncthreads();
        s[t] += add;
        __syncthreads();
    }
    if (g < n) off[g] = s[t] - v;
    if (t == 255) bsum[blockIdx.x] = s[255];
}

__global__ void scan_bsum(int* __restrict__ bsum, int nb)
{
    __shared__ int s[512];
    int t = threadIdx.x;
    int v = (t < nb) ? bsum[t] : 0;
    s[t] = v; __syncthreads();
    for (int d = 1; d < 512; d <<= 1) {
        int add = (t >= d) ? s[t - d] : 0;
        __syncthreads();
        s[t] += add;
        __syncthreads();
    }
    if (t < nb) bsum[t] = s[t] - v;
}

__global__ void scan_add(int* __restrict__ off, const int* __restrict__ bsum,
                         int* __restrict__ cur, int n)
{
    int g = blockIdx.x * 256 + threadIdx.x;
    if (g < n) { int o = off[g] + bsum[blockIdx.x]; off[g] = o; cur[g] = o; }
}

__global__ void scatter_edges(const int* __restrict__ eidx, int* __restrict__ cur,
                              int* __restrict__ srcp, int* __restrict__ eord)
{
    int e = blockIdx.x * 256 + threadIdx.x;
    if (e < NE) {
        int s = eidx[e], d = eidx[NE + e];
        int pos = atomicAdd(&cur[d + (e >= EHALF ? NN : 0)], 1);
        srcp[pos] = s;
        eord[pos] = e;
    }
}

// ------- eattr gather -> CSR-ordered bf16 [NE][128] (zero-padded) ---------
__global__ __launch_bounds__(256)
void cvt_gather(const float* __restrict__ eatt, const int* __restrict__ eord,
                __bf16* __restrict__ ebf)
{
    int i = blockIdx.x * 256 + threadIdx.x;     // NE*16 threads, 8 cols each
    int row = i >> 4, oct = i & 15;
    if (row >= NE) return;
    const float* p = eatt + (size_t)eord[row] * 100;
    bf16x8 o;
    if (oct < 12) {
        float4 v0 = *(const float4*)(p + oct * 8);
        float4 v1 = *(const float4*)(p + oct * 8 + 4);
        o[0] = (__bf16)v0.x; o[1] = (__bf16)v0.y; o[2] = (__bf16)v0.z; o[3] = (__bf16)v0.w;
        o[4] = (__bf16)v1.x; o[5] = (__bf16)v1.y; o[6] = (__bf16)v1.z; o[7] = (__bf16)v1.w;
    } else if (oct == 12) {
        float4 v0 = *(const float4*)(p + 96);
        o[0] = (__bf16)v0.x; o[1] = (__bf16)v0.y; o[2] = (__bf16)v0.z; o[3] = (__bf16)v0.w;
        o[4] = (__bf16)0.f; o[5] = (__bf16)0.f; o[6] = (__bf16)0.f; o[7] = (__bf16)0.f;
    } else {
        #pragma unroll
        for (int j = 0; j < 8; ++j) o[j] = (__bf16)0.f;
    }
    *(bf16x8*)(ebf + (size_t)row * 128 + oct * 8) = o;
}

// ---------------- mt_all: all 4 edge mid-GEMMs, 64-row tiles ------------
// grid 25000: quarter q = bid/6250 (0: MT1 half-a, 1: MT1 half-b, 2: MT2
// half-a, 3: MT2 half-b); 64 rows per block. W fragments from pre-transposed
// Wt[q][col][k] bf16 (16 vector loads). Input LDS-free; C staged in LDS
// (stride 116, conflict-free). Wave-private copy-out (wave (mh,nq) wrote
// rows [mh*32,+32) x cols [nq*64,+64) of ct) -> no barrier.
__global__ __launch_bounds__(256)
void mt_all(const __bf16* __restrict__ ebf,    // [NE][128] CSR order
            const __bf16* __restrict__ Wt,     // [4][128][128]
            __bf16* __restrict__ MT1,          // [NE][112] CSR order
            __bf16* __restrict__ MT2)          // [NE][112] CSR order
{
    __shared__ __align__(16) __bf16 ct[64 * 116];   // 14.8 KB
    const int t = threadIdx.x;
    const int lane = t & 63, w = t >> 6;
    const int mh = w & 1, nq = w >> 1;
    const int l15 = lane & 15, l4 = lane >> 4;
    const int q = blockIdx.x / 6250;
    const int tile = blockIdx.x - q * 6250;
    const size_t row0 = (size_t)tile * 64 + (size_t)(q & 1) * EHALF;
    __bf16* MT = (q < 2) ? MT1 : MT2;
    const __bf16* Wq = Wt + (size_t)q * 16384;

    bf16x8 wf[4][4];
    const int colbase = nq * 64 + l15;
    #pragma unroll
    for (int nt = 0; nt < 4; ++nt)
        #pragma unroll
        for (int ks = 0; ks < 4; ++ks)
            wf[nt][ks] = *(const bf16x8*)(Wq + (colbase + nt * 16) * 128 +
                                          ks * 32 + l4 * 8);

    f32x4 c[2][4] = {};
    #pragma unroll
    for (int ks = 0; ks < 4; ++ks) {
        #pragma unroll
        for (int mt = 0; mt < 2; ++mt) {
            size_t row = row0 + mh * 32 + mt * 16 + l15;
            bf16x8 a = *(const bf16x8*)(ebf + row * 128 + ks * 32 + l4 * 8);
            #pragma unroll
            for (int nt = 0; nt < 4; ++nt)
                c[mt][nt] = __builtin_amdgcn_mfma_f32_16x16x32_bf16(
                    a, wf[nt][ks], c[mt][nt], 0, 0, 0);
        }
    }
    #pragma unroll
    for (int mt = 0; mt < 2; ++mt) {
        #pragma unroll
        for (int nt = 0; nt < 4; ++nt) {
            int col = colbase + nt * 16;
            if (col < 112) {
                #pragma unroll
                for (int r = 0; r < 4; ++r) {
                    int lrow = mh * 32 + mt * 16 + l4 * 4 + r;
                    ct[lrow * 116 + col] = (__bf16)c[mt][nt][r];
                }
            }
        }
    }
    // wave-private copy-out: rows [mh*32,+32), cols nq? 64..111 : 0..63
    const int rbase = mh * 32;
    __bf16* gout = MT + (row0 + rbase) * 112;
    if (nq == 0) {
        #pragma unroll
        for (int k = 0; k < 8; ++k) {
            int i = lane + 64 * k;
            int row = i >> 4, ch = i & 15;
            *(uint2*)(gout + row * 112 + ch * 4) =
                *(const uint2*)(ct + (rbase + row) * 116 + ch * 4);
        }
    } else {
        #pragma unroll
        for (int k = 0; k < 6; ++k) {
            int i = lane + 64 * k;
            int row = i / 12, ch = i - row * 12;
            *(uint2*)(gout + row * 112 + 64 + ch * 4) =
                *(const uint2*)(ct + (rbase + row) * 116 + 64 + ch * 4);
        }
    }
}

// ---------------- edge_aggr3: both phases, register accumulation ----------
template<int ND, int NTS>
__global__ __launch_bounds__(256)
void edge_aggr3(const __bf16* __restrict__ MT,    // [NE][112] CSR order
                const int* __restrict__ srcp,     // [NE] src per CSR position
                const int* __restrict__ off,      // [NN2]
                const __bf16* __restrict__ NT,    // [NN][NTS] bf16
                const float* __restrict__ self,   // [NN][ND] fp32
                float* __restrict__ aggr,         // [NN][112]
                int blkd0, int blks0, int blkd1, int blks1)
{
    const int t = threadIdx.x;
    const int lane = t & 63, wv = t >> 6;
    const int c0 = lane * 2;
    const bool a0 = c0 < ND, a1 = c0 + 1 < ND;
    const int n = blockIdx.x * 4 + wv;     // one node per wave

    float acc0 = 0.f, acc1 = 0.f;

    #pragma unroll
    for (int phase = 0; phase < 2; ++phase) {
        const int blkd = phase ? blkd1 : blkd0;
        const int blks = phase ? blks1 : blks0;
        const int idx = phase * NN + n;
        const int pb = off[idx];
        const int pe = (idx + 1 == NN2) ? NE : off[idx + 1];

        float nd0 = 0.f, nd1 = 0.f;
        if (a0) {
            unsigned nd = *(const unsigned*)(NT + (size_t)n * NTS + blkd + c0);
            nd0 = bf16lo(nd); nd1 = bf16hi(nd);
        }

        for (int p = pb; p < pe; p += GB) {
            int ok[GB], ss[GB];
            #pragma unroll
            for (int i = 0; i < GB; ++i) {
                int pp = p + i;
                ok[i] = pp < pe;
                ss[i] = ok[i] ? srcp[pp] : 0;
            }
            unsigned mtw[GB], nsw[GB];
            #pragma unroll
            for (int i = 0; i < GB; ++i) {
                mtw[i] = 0u; nsw[i] = 0u;
                if (ok[i] && a0) {
                    mtw[i] = *(const unsigned*)(MT + (size_t)(p + i) * 112 + c0);
                    nsw[i] = *(const unsigned*)(NT + (size_t)ss[i] * NTS + blks + c0);
                }
            }
            #pragma unroll
            for (int i = 0; i < GB; ++i) {
                if (!ok[i]) continue;             // wave-uniform
                acc0 += fmaxf(bf16lo(mtw[i]) + nd0 + bf16lo(nsw[i]), 0.f);
                acc1 += fmaxf(bf16hi(mtw[i]) + nd1 + bf16hi(nsw[i]), 0.f);
            }
        }
    }

    if (c0 < 112) {
        const size_t g0 = (size_t)n * 112 + c0;
        aggr[g0]     = a0 ? (acc0 + self[(size_t)n * ND + c0])     : 0.f;
        aggr[g0 + 1] = a1 ? (acc1 + self[(size_t)n * ND + c0 + 1]) : 0.f;
    }
}

// ---- weight assembly: padded concat blocks + transposed mid blocks -------
__global__ void assemble(const float* __restrict__ l1a, const float* __restrict__ l1ab,
                         const float* __restrict__ l1b, const float* __restrict__ l1bb,
                         const float* __restrict__ l2a, const float* __restrict__ l2ab,
                         const float* __restrict__ l2b, const float* __restrict__ l2bb,
                         float* __restrict__ W1, float* __restrict__ b1,
                         float* __restrict__ W2, float* __restrict__ b2,
                         __bf16* __restrict__ Wt)
{
    int i = blockIdx.x * 256 + threadIdx.x;
    if (i < 107 * 432) {
        int k = i / 432, c = i % 432;
        int q = c / 108, cc = c - q * 108;
        float v = 0.f;
        if (cc < 107) {
            if (q == 0)      v = l1a[k * 107 + cc];
            else if (q == 1) v = l1a[(207 + k) * 107 + cc];
            else if (q == 2) v = l1b[k * 107 + cc];
            else             v = l1b[(207 + k) * 107 + cc];
        }
        W1[i] = v;
    }
    if (i < 432) {
        int q = i / 108, cc = i - q * 108;
        b1[i] = (cc < 107) ? (q == 0 ? l1ab[cc] : (q == 3 ? l1bb[cc] : 0.f)) : 0.f;
    }
    if (i < 100 * 416) {
        int k = i / 416, c = i % 416;
        int q = c / 104, cc = c - q * 104;
        float v = 0.f;
        if (cc < 100) {
            if (q == 0)      v = l2a[k * 100 + cc];
            else if (q == 1) v = l2a[(200 + k) * 100 + cc];
            else if (q == 2) v = l2b[k * 100 + cc];
            else             v = l2b[(200 + k) * 100 + cc];
        }
        W2[i] = v;
    }
    if (i < 416) {
        int q = i / 104, cc = i - q * 104;
        b2[i] = (cc < 100) ? (q == 0 ? l2ab[cc] : (q == 3 ? l2bb[cc] : 0.f)) : 0.f;
    }
    if (i < 4 * 128 * 128) {
        int q = i >> 14, col = (i >> 7) & 127, k = i & 127;
        const float* Wm = (q == 0) ? l1a + 107 * 107 :
                          (q == 1) ? l1b + 107 * 107 :
                          (q == 2) ? l2a + 100 * 100 : l2b + 100 * 100;
        int ND = (q < 2) ? 107 : 100;
        float v = (k < 100 && col < ND) ? Wm[k * ND + col] : 0.f;
        Wt[i] = (__bf16)v;
    }
}

// ---- xposeW: transpose all dense-GEMM weights into bf16 [1344][128] ------
// segments (colPad, colReal, K, stride): W1(448,432,107,432) W2(448,416,100,416)
// m1w1(128,100,107,100) m1w2(128,100,100,100) m2w1(64,64,100,64) m2w2(128,100,64,100)
__global__ __launch_bounds__(256)
void xposeW(const float* __restrict__ W1, const float* __restrict__ W2,
            const float* __restrict__ m1w1, const float* __restrict__ m1w2,
            const float* __restrict__ m2w1, const float* __restrict__ m2w2,
            __bf16* __restrict__ WT)
{
    int i = blockIdx.x * 256 + threadIdx.x;
    if (i >= 1344 * 128) return;
    int c = i >> 7, k = i & 127;
    const float* src; int lc, cr, K, st;
    if (c < 448)      { src = W1;   lc = c;        cr = 432; K = 107; st = 432; }
    else if (c < 896) { src = W2;   lc = c - 448;  cr = 416; K = 100; st = 416; }
    else if (c < 1024){ src = m1w1; lc = c - 896;  cr = 100; K = 107; st = 100; }
    else if (c < 1152){ src = m1w2; lc = c - 1024; cr = 100; K = 100; st = 100; }
    else if (c < 1216){ src = m2w1; lc = c - 1152; cr = 64;  K = 100; st = 64;  }
    else              { src = m2w2; lc = c - 1216; cr = 100; K = 64;  st = 100; }
    float v = (lc < cr && k < K) ? src[k * st + lc] : 0.f;
    WT[i] = (__bf16)v;
}

extern "C" void kernel_launch(void* const* d_in, const int* in_sizes, int n_in,
                              void* d_out, int out_size, void* d_ws, size_t ws_size,
                              hipStream_t stream)
{
    const float* x    = (const float*)d_in[0];
    const int*   eidx = (const int*)d_in[1];
    const float* eatt = (const float*)d_in[2];
    const float* l1aw = (const float*)d_in[3];
    const float* l1ab = (const float*)d_in[4];
    const float* l1bw = (const float*)d_in[5];
    const float* l1bb = (const float*)d_in[6];
    const float* m1w1 = (const float*)d_in[7];
    const float* m1b1 = (const float*)d_in[8];
    const float* m1w2 = (const float*)d_in[9];
    const float* m1b2 = (const float*)d_in[10];
    const float* l2aw = (const float*)d_in[11];
    const float* l2ab = (const float*)d_in[12];
    const float* l2bw = (const float*)d_in[13];
    const float* l2bb = (const float*)d_in[14];
    const float* m2w1 = (const float*)d_in[15];
    const float* m2b1 = (const float*)d_in[16];
    const float* m2w2 = (const float*)d_in[17];
    const float* m2b2 = (const float*)d_in[18];
    float* out = (float*)d_out;

    // workspace layout (4-byte units), ~660 MB
    float*  ws   = (float*)d_ws;
    __bf16* NTbf = (__bf16*)ws;                         // 50000*432 bf16
    float*  bufA = ws + 10800000;                       // 50000*112 fp32
    float*  bufC = bufA + 5600000;                      // 50000*100 fp32 (h)
    float*  W1   = bufC + 5000000;                      // 46,224
    float*  b1v  = W1 + 46224;                          // 432
    float*  W2   = b1v + 432;                           // 41,600
    float*  b2v  = W2 + 41600;                          // 416
    __bf16* Wt   = (__bf16*)(b2v + 416);                // 4*128*128 bf16
    __bf16* WT   = Wt + 65536;                          // 1344*128 bf16
    int*    off  = (int*)(WT + 172032);                 // 100,000
    int*    cur  = off + NN2;                           // 100,000
    int*    bsum = cur + NN2;                           // 512
    int*    srcp = bsum + 512;                          // 800,000
    int*    eord = srcp + NE;                           // 800,000
    __bf16* ebf  = (__bf16*)(eord + NE);                // NE*128 bf16
    __bf16* MT1  = ebf + (size_t)NE * 128;              // NE*112 bf16
    __bf16* MT2  = MT1 + (size_t)NE * 112;              // NE*112 bf16
    float*  bufB = (float*)MT1;                         // t1/t2 alias (MT1 consumed)

    const int* dst = eidx + NE;

    assemble<<<256, 256, 0, stream>>>(l1aw, l1ab, l1bw, l1bb, l2aw, l2ab, l2bw, l2bb,
                                      W1, b1v, W2, b2v, Wt);
    xposeW<<<672, 256, 0, stream>>>(W1, W2, m1w1, m1w2, m2w1, m2w2, WT);

    // ---- CSR build (dst-sorted, per half; emits srcp/eord) ----
    zero_ints<<<(NN2 + 255) / 256, 256, 0, stream>>>(cur, NN2);
    count_edges<<<(NE + 255) / 256, 256, 0, stream>>>(dst, cur);
    scan_blocks<<<(NN2 + 255) / 256, 256, 0, stream>>>(cur, off, bsum, NN2);
    scan_bsum<<<1, 512, 0, stream>>>(bsum, (NN2 + 255) / 256);
    scan_add<<<(NN2 + 255) / 256, 256, 0, stream>>>(off, bsum, cur, NN2);
    scatter_edges<<<(NE + 255) / 256, 256, 0, stream>>>(eidx, cur, srcp, eord);

    // ---- eattr gather -> CSR-ordered bf16[128] ----
    cvt_gather<<<NE * 16 / 256, 256, 0, stream>>>(eatt, eord, ebf);

    // ---- all 4 edge mid-GEMMs in one dispatch (64-row tiles) ----
    mt_all<<<25000, 256, 0, stream>>>(ebf, Wt, MT1, MT2);

    const int AG = NN / 4;   // 12500 blocks: 4 waves x 1 node each

    // ---- conv1 ----
    mm_bf16t<107, true><<<dim3(98, 7), 256, 0, stream>>>(x, WT, b1v, NTbf,
                                                         NN, 432, 432, 4, 0);
    edge_aggr3<107, 432><<<AG, 256, 0, stream>>>(MT1, srcp, off, NTbf, x, bufA,
                                                 0, 108, 324, 216);
    mm_bf16t<112, false><<<dim3(98, 2), 256, 0, stream>>>(bufA, WT + 896 * 128,
                                                          m1b1, bufB, NN, 100, 100, 4, 1);
    mm_bf16t<100, false><<<dim3(98, 2), 256, 0, stream>>>(bufB, WT + 1024 * 128,
                                                          m1b2, bufC, NN, 100, 100, 4, 1);

    // ---- conv2 ----  (h in bufC)
    mm_bf16t<100, true><<<dim3(98, 7), 256, 0, stream>>>(bufC, WT + 448 * 128,
                                                         b2v, NTbf, NN, 416, 416, 4, 0);
    edge_aggr3<100, 416><<<AG, 256, 0, stream>>>(MT2, srcp, off, NTbf, bufC, bufA,
                                                 0, 104, 312, 208);
    mm_bf16t<112, false><<<dim3(98, 1), 256, 0, stream>>>(bufA, WT + 1152 * 128,
                                                          m2b1, bufB, NN, 64, 64, 4, 1);
    mm_bf16t<64, false><<<dim3(98, 2), 256, 0, stream>>>(bufB, WT + 1216 * 128,
                                                         m2b2, out, NN, 100, 100, 4, 0);
}

// Round 17
// 972.099 us; speedup vs baseline: 2.3948x; 1.0474x over previous
//
#include <hip/hip_runtime.h>

// RuleGraphNet: 2x TripleConv(+mlp), N=50000 nodes, E=800000 edges.
// Pipeline: all 4 edge mid-GEMMs in one dispatch (mt_all: 128-row tiles,
// DIRECT gathered fp32 eatt input with in-register bf16 convert — no ebf
// materialization; wave-private copy-out, no barriers); MT1/MT2 CSR-ordered
// -> sequential aggregation; NT bf16; aggregation wave owns 1 dst node, lane
// owns a column pair, register accumulation over both phases, self fused.
// ALL dense GEMMs use pre-transposed bf16 weight tables.

#define NN 50000
#define NE 800000
#define EHALF 400000
#define NN2 100000
#define GB 8            // edges batched per gather group

typedef __attribute__((ext_vector_type(4))) float  f32x4;
typedef __attribute__((ext_vector_type(8))) __bf16 bf16x8;
typedef __attribute__((ext_vector_type(4))) __bf16 bf16x4;

__device__ __forceinline__ float bf16lo(unsigned u) {
    union { unsigned u; float f; } c; c.u = u << 16; return c.f;
}
__device__ __forceinline__ float bf16hi(unsigned u) {
    union { unsigned u; float f; } c; c.u = u & 0xffff0000u; return c.f;
}

// ------- generic bf16 MFMA GEMM, W from pre-transposed bf16 table ---------
template<int K, bool OBF16>
__global__ __launch_bounds__(256)
void mm_bf16t(const float* __restrict__ A, const __bf16* __restrict__ Wtt,
              const float* __restrict__ bias, void* __restrict__ Outp,
              int M, int N, int ldo, int RT, int relu)
{
    __shared__ __align__(16) __bf16 et[128 * 128];
    const int t = threadIdx.x;
    const int lane = t & 63, w = t >> 6;
    const int mh = w & 1, nh = w >> 1;
    const int l15 = lane & 15, l4 = lane >> 4;
    const int cb = blockIdx.y * 64;

    bf16x8 wf[2][4];
    const int colbase = cb + nh * 32 + l15;
    #pragma unroll
    for (int nt = 0; nt < 2; ++nt)
        #pragma unroll
        for (int ks = 0; ks < 4; ++ks)
            wf[nt][ks] = *(const bf16x8*)(Wtt + (colbase + nt * 16) * 128 +
                                          ks * 32 + l4 * 8);
    float bv[2] = {0.f, 0.f};
    if (bias) {
        #pragma unroll
        for (int nt = 0; nt < 2; ++nt) {
            int col = colbase + nt * 16;
            if (col < N) bv[nt] = bias[col];
        }
    }

    for (int it = 0; it < RT; ++it) {
        const int row0 = (blockIdx.x * RT + it) * 128;
        if (row0 >= M) break;
        __syncthreads();
        if constexpr (K % 4 == 0) {
            constexpr int QK = K / 4;
            for (int i = t; i < 128 * QK; i += 256) {
                int row = i / QK, q = i - row * QK;
                int gr = row0 + row;
                float4 v = {0.f, 0.f, 0.f, 0.f};
                if (gr < M) v = *(const float4*)(A + (size_t)gr * K + q * 4);
                bf16x4 b;
                b[0] = (__bf16)v.x; b[1] = (__bf16)v.y;
                b[2] = (__bf16)v.z; b[3] = (__bf16)v.w;
                *(bf16x4*)(et + row * 128 + ((q * 4) ^ ((row & 7) << 3))) = b;
            }
            constexpr int QP = (128 - K) / 4;
            if constexpr (QP > 0) {
                for (int i = t; i < 128 * QP; i += 256) {
                    int row = i / QP, q = QK + (i - (i / QP) * QP);
                    bf16x4 z;
                    z[0] = (__bf16)0.f; z[1] = (__bf16)0.f;
                    z[2] = (__bf16)0.f; z[3] = (__bf16)0.f;
                    *(bf16x4*)(et + row * 128 + ((q * 4) ^ ((row & 7) << 3))) = z;
                }
            }
        } else {
            for (int i = t; i < 128 * 128; i += 256) {
                int row = i >> 7, k = i & 127;
                int gr = row0 + row;
                float v = (k < K && gr < M) ? A[(size_t)gr * K + k] : 0.f;
                et[row * 128 + (k ^ ((row & 7) << 3))] = (__bf16)v;
            }
        }
        __syncthreads();

        f32x4 c[4][2] = {};
        #pragma unroll
        for (int ks = 0; ks < 4; ++ks) {
            #pragma unroll
            for (int mt = 0; mt < 4; ++mt) {
                int arow = mh * 64 + mt * 16 + l15;
                bf16x8 a = *(const bf16x8*)(et + arow * 128 +
                                            ((ks * 32 + l4 * 8) ^ ((l15 & 7) << 3)));
                c[mt][0] = __builtin_amdgcn_mfma_f32_16x16x32_bf16(a, wf[0][ks], c[mt][0], 0, 0, 0);
                c[mt][1] = __builtin_amdgcn_mfma_f32_16x16x32_bf16(a, wf[1][ks], c[mt][1], 0, 0, 0);
            }
        }

        #pragma unroll
        for (int mt = 0; mt < 4; ++mt) {
            #pragma unroll
            for (int nt = 0; nt < 2; ++nt) {
                int col = colbase + nt * 16;
                #pragma unroll
                for (int r = 0; r < 4; ++r) {
                    int row = row0 + mh * 64 + mt * 16 + l4 * 4 + r;
                    if constexpr (OBF16) {
                        if (row < M && col < ldo)
                            ((__bf16*)Outp)[(size_t)row * ldo + col] =
                                (__bf16)(c[mt][nt][r] + bv[nt]);
                    } else {
                        if (row < M && col < N) {
                            float v = c[mt][nt][r] + bv[nt];
                            if (relu) v = fmaxf(v, 0.f);
                            ((float*)Outp)[(size_t)row * ldo + col] = v;
                        }
                    }
                }
            }
        }
    }
}

// ---------------- CSR build (edges sorted by dst, per half) ----------------
__global__ void zero_ints(int* __restrict__ p, int n)
{
    int i = blockIdx.x * 256 + threadIdx.x;
    if (i < n) p[i] = 0;
}

__global__ void count_edges(const int* __restrict__ dst, int* __restrict__ cnt)
{
    int e = blockIdx.x * 256 + threadIdx.x;
    if (e < NE) atomicAdd(&cnt[dst[e] + (e >= EHALF ? NN : 0)], 1);
}

__global__ void scan_blocks(const int* __restrict__ cnt, int* __restrict__ off,
                            int* __restrict__ bsum, int n)
{
    __shared__ int s[256];
    int t = threadIdx.x, g = blockIdx.x * 256 + t;
    int v = (g < n) ? cnt[g] : 0;
    s[t] = v; __syncthreads();
    for (int d = 1; d < 256; d <<= 1) {
        int add = (t >= d) ? s[t - d] : 0;
        __syncthreads();
        s[t] += add;
        __syncthreads();
    }
    if (g < n) off[g] = s[t] - v;
    if (t == 255) bsum[blockIdx.x] = s[255];
}

__global__ void scan_bsum(int* __restrict__ bsum, int nb)
{
    __shared__ int s[512];
    int t = threadIdx.x;
    int v = (t < nb) ? bsum[t] : 0;
    s[t] = v; __syncthreads();
    for (int d = 1; d < 512; d <<= 1) {
        int add = (t >= d) ? s[t - d] : 0;
        __syncthreads();
        s[t] += add;
        __syncthreads();
    }
    if (t < nb) bsum[t] = s[t] - v;
}

__global__ void scan_add(int* __restrict__ off, const int* __restrict__ bsum,
                         int* __restrict__ cur, int n)
{
    int g = blockIdx.x * 256 + threadIdx.x;
    if (g < n) { int o = off[g] + bsum[blockIdx.x]; off[g] = o; cur[g] = o; }
}

__global__ void scatter_edges(const int* __restrict__ eidx, int* __restrict__ cur,
                              int* __restrict__ srcp, int* __restrict__ eord)
{
    int e = blockIdx.x * 256 + threadIdx.x;
    if (e < NE) {
        int s = eidx[e], d = eidx[NE + e];
        int pos = atomicAdd(&cur[d + (e >= EHALF ? NN : 0)], 1);
        srcp[pos] = s;
        eord[pos] = e;
    }
}

// ---------------- mt_all: all 4 edge mid-GEMMs, direct eatt input ---------
// grid 12500: quarter q = bid/3125 (0: MT1 half-a, 1: MT1 half-b, 2: MT2
// half-a, 3: MT2 half-b); 128 rows per block. A-fragments read straight from
// gathered fp32 eatt rows (eord indirection) and converted to bf16 in
// registers (k >= 100 zero via guards; last valid load starts at k=96).
// W fragments from pre-transposed Wt (16 vector loads). C staged in LDS
// (stride 116, conflict-free); wave-private copy-out -> no barriers.
__global__ __launch_bounds__(256)
void mt_all(const float* __restrict__ eatt,   // [NE][100] original order
            const int* __restrict__ eord,     // [NE] CSR pos -> edge id
            const __bf16* __restrict__ Wt,    // [4][128][128]
            __bf16* __restrict__ MT1,         // [NE][112] CSR order
            __bf16* __restrict__ MT2)         // [NE][112] CSR order
{
    __shared__ __align__(16) __bf16 ct[128 * 116];   // 29.7 KB
    const int t = threadIdx.x;
    const int lane = t & 63, w = t >> 6;
    const int mh = w & 1, nq = w >> 1;
    const int l15 = lane & 15, l4 = lane >> 4;
    const int q = blockIdx.x / 3125;
    const int tile = blockIdx.x - q * 3125;
    const size_t row0 = (size_t)tile * 128 + (size_t)(q & 1) * EHALF;
    __bf16* MT = (q < 2) ? MT1 : MT2;
    const __bf16* Wq = Wt + (size_t)q * 16384;

    bf16x8 wf[4][4];
    const int colbase = nq * 64 + l15;
    #pragma unroll
    for (int nt = 0; nt < 4; ++nt)
        #pragma unroll
        for (int ks = 0; ks < 4; ++ks)
            wf[nt][ks] = *(const bf16x8*)(Wq + (colbase + nt * 16) * 128 +
                                          ks * 32 + l4 * 8);

    // this lane's 4 source-row bases (per m-tile)
    const float* ep[4];
    #pragma unroll
    for (int mt = 0; mt < 4; ++mt) {
        size_t row = row0 + mh * 64 + mt * 16 + l15;
        ep[mt] = eatt + (size_t)eord[row] * 100;
    }

    f32x4 c[4][4] = {};
    #pragma unroll
    for (int ks = 0; ks < 4; ++ks) {
        const int bk = ks * 32 + l4 * 8;
        #pragma unroll
        for (int mt = 0; mt < 4; ++mt) {
            float4 v0 = {0.f, 0.f, 0.f, 0.f}, v1 = {0.f, 0.f, 0.f, 0.f};
            if (bk < 100)     v0 = *(const float4*)(ep[mt] + bk);
            if (bk + 4 < 100) v1 = *(const float4*)(ep[mt] + bk + 4);
            bf16x8 a;
            a[0] = (__bf16)v0.x; a[1] = (__bf16)v0.y;
            a[2] = (__bf16)v0.z; a[3] = (__bf16)v0.w;
            a[4] = (__bf16)v1.x; a[5] = (__bf16)v1.y;
            a[6] = (__bf16)v1.z; a[7] = (__bf16)v1.w;
            #pragma unroll
            for (int nt = 0; nt < 4; ++nt)
                c[mt][nt] = __builtin_amdgcn_mfma_f32_16x16x32_bf16(
                    a, wf[nt][ks], c[mt][nt], 0, 0, 0);
        }
    }
    #pragma unroll
    for (int mt = 0; mt < 4; ++mt) {
        #pragma unroll
        for (int nt = 0; nt < 4; ++nt) {
            int col = colbase + nt * 16;
            if (col < 112) {
                #pragma unroll
                for (int r = 0; r < 4; ++r) {
                    int lrow = mh * 64 + mt * 16 + l4 * 4 + r;
                    ct[lrow * 116 + col] = (__bf16)c[mt][nt][r];
                }
            }
        }
    }
    // wave-private copy-out: rows [mh*64,+64), cols nq? 64..111 : 0..63
    const int rbase = mh * 64;
    __bf16* gout = MT + (row0 + rbase) * 112;
    if (nq == 0) {
        #pragma unroll
        for (int k = 0; k < 16; ++k) {
            int i = lane + 64 * k;
            int row = i >> 4, ch = i & 15;
            *(uint2*)(gout + row * 112 + ch * 4) =
                *(const uint2*)(ct + (rbase + row) * 116 + ch * 4);
        }
    } else {
        #pragma unroll
        for (int k = 0; k < 12; ++k) {
            int i = lane + 64 * k;
            int row = i / 12, ch = i - row * 12;
            *(uint2*)(gout + row * 112 + 64 + ch * 4) =
                *(const uint2*)(ct + (rbase + row) * 116 + 64 + ch * 4);
        }
    }
}

// ---------------- edge_aggr3: both phases, register accumulation ----------
template<int ND, int NTS>
__global__ __launch_bounds__(256)
void edge_aggr3(const __bf16* __restrict__ MT,    // [NE][112] CSR order
                const int* __restrict__ srcp,     // [NE] src per CSR position
                const int* __restrict__ off,      // [NN2]
                const __bf16* __restrict__ NT,    // [NN][NTS] bf16
                const float* __restrict__ self,   // [NN][ND] fp32
                float* __restrict__ aggr,         // [NN][112]
                int blkd0, int blks0, int blkd1, int blks1)
{
    const int t = threadIdx.x;
    const int lane = t & 63, wv = t >> 6;
    const int c0 = lane * 2;
    const bool a0 = c0 < ND, a1 = c0 + 1 < ND;
    const int n = blockIdx.x * 4 + wv;     // one node per wave

    float acc0 = 0.f, acc1 = 0.f;

    #pragma unroll
    for (int phase = 0; phase < 2; ++phase) {
        const int blkd = phase ? blkd1 : blkd0;
        const int blks = phase ? blks1 : blks0;
        const int idx = phase * NN + n;
        const int pb = off[idx];
        const int pe = (idx + 1 == NN2) ? NE : off[idx + 1];

        float nd0 = 0.f, nd1 = 0.f;
        if (a0) {
            unsigned nd = *(const unsigned*)(NT + (size_t)n * NTS + blkd + c0);
            nd0 = bf16lo(nd); nd1 = bf16hi(nd);
        }

        for (int p = pb; p < pe; p += GB) {
            int ok[GB], ss[GB];
            #pragma unroll
            for (int i = 0; i < GB; ++i) {
                int pp = p + i;
                ok[i] = pp < pe;
                ss[i] = ok[i] ? srcp[pp] : 0;
            }
            unsigned mtw[GB], nsw[GB];
            #pragma unroll
            for (int i = 0; i < GB; ++i) {
                mtw[i] = 0u; nsw[i] = 0u;
                if (ok[i] && a0) {
                    mtw[i] = *(const unsigned*)(MT + (size_t)(p + i) * 112 + c0);
                    nsw[i] = *(const unsigned*)(NT + (size_t)ss[i] * NTS + blks + c0);
                }
            }
            #pragma unroll
            for (int i = 0; i < GB; ++i) {
                if (!ok[i]) continue;             // wave-uniform
                acc0 += fmaxf(bf16lo(mtw[i]) + nd0 + bf16lo(nsw[i]), 0.f);
                acc1 += fmaxf(bf16hi(mtw[i]) + nd1 + bf16hi(nsw[i]), 0.f);
            }
        }
    }

    if (c0 < 112) {
        const size_t g0 = (size_t)n * 112 + c0;
        aggr[g0]     = a0 ? (acc0 + self[(size_t)n * ND + c0])     : 0.f;
        aggr[g0 + 1] = a1 ? (acc1 + self[(size_t)n * ND + c0 + 1]) : 0.f;
    }
}

// ---- weight assembly: padded concat blocks + transposed mid blocks -------
__global__ void assemble(const float* __restrict__ l1a, const float* __restrict__ l1ab,
                         const float* __restrict__ l1b, const float* __restrict__ l1bb,
                         const float* __restrict__ l2a, const float* __restrict__ l2ab,
                         const float* __restrict__ l2b, const float* __restrict__ l2bb,
                         float* __restrict__ W1, float* __restrict__ b1,
                         float* __restrict__ W2, float* __restrict__ b2,
                         __bf16* __restrict__ Wt)
{
    int i = blockIdx.x * 256 + threadIdx.x;
    if (i < 107 * 432) {
        int k = i / 432, c = i % 432;
        int q = c / 108, cc = c - q * 108;
        float v = 0.f;
        if (cc < 107) {
            if (q == 0)      v = l1a[k * 107 + cc];
            else if (q == 1) v = l1a[(207 + k) * 107 + cc];
            else if (q == 2) v = l1b[k * 107 + cc];
            else             v = l1b[(207 + k) * 107 + cc];
        }
        W1[i] = v;
    }
    if (i < 432) {
        int q = i / 108, cc = i - q * 108;
        b1[i] = (cc < 107) ? (q == 0 ? l1ab[cc] : (q == 3 ? l1bb[cc] : 0.f)) : 0.f;
    }
    if (i < 100 * 416) {
        int k = i / 416, c = i % 416;
        int q = c / 104, cc = c - q * 104;
        float v = 0.f;
        if (cc < 100) {
            if (q == 0)      v = l2a[k * 100 + cc];
            else if (q == 1) v = l2a[(200 + k) * 100 + cc];
            else if (q == 2) v = l2b[k * 100 + cc];
            else             v = l2b[(200 + k) * 100 + cc];
        }
        W2[i] = v;
    }
    if (i < 416) {
        int q = i / 104, cc = i - q * 104;
        b2[i] = (cc < 100) ? (q == 0 ? l2ab[cc] : (q == 3 ? l2bb[cc] : 0.f)) : 0.f;
    }
    if (i < 4 * 128 * 128) {
        int q = i >> 14, col = (i >> 7) & 127, k = i & 127;
        const float* Wm = (q == 0) ? l1a + 107 * 107 :
                          (q == 1) ? l1b + 107 * 107 :
                          (q == 2) ? l2a + 100 * 100 : l2b + 100 * 100;
        int ND = (q < 2) ? 107 : 100;
        float v = (k < 100 && col < ND) ? Wm[k * ND + col] : 0.f;
        Wt[i] = (__bf16)v;
    }
}

// ---- xposeW: transpose all dense-GEMM weights into bf16 [1344][128] ------
__global__ __launch_bounds__(256)
void xposeW(const float* __restrict__ W1, const float* __restrict__ W2,
            const float* __restrict__ m1w1, const float* __restrict__ m1w2,
            const float* __restrict__ m2w1, const float* __restrict__ m2w2,
            __bf16* __restrict__ WT)
{
    int i = blockIdx.x * 256 + threadIdx.x;
    if (i >= 1344 * 128) return;
    int c = i >> 7, k = i & 127;
    const float* src; int lc, cr, K, st;
    if (c < 448)      { src = W1;   lc = c;        cr = 432; K = 107; st = 432; }
    else if (c < 896) { src = W2;   lc = c - 448;  cr = 416; K = 100; st = 416; }
    else if (c < 1024){ src = m1w1; lc = c - 896;  cr = 100; K = 107; st = 100; }
    else if (c < 1152){ src = m1w2; lc = c - 1024; cr = 100; K = 100; st = 100; }
    else if (c < 1216){ src = m2w1; lc = c - 1152; cr = 64;  K = 100; st = 64;  }
    else              { src = m2w2; lc = c - 1216; cr = 100; K = 64;  st = 100; }
    float v = (lc < cr && k < K) ? src[k * st + lc] : 0.f;
    WT[i] = (__bf16)v;
}

extern "C" void kernel_launch(void* const* d_in, const int* in_sizes, int n_in,
                              void* d_out, int out_size, void* d_ws, size_t ws_size,
                              hipStream_t stream)
{
    const float* x    = (const float*)d_in[0];
    const int*   eidx = (const int*)d_in[1];
    const float* eatt = (const float*)d_in[2];
    const float* l1aw = (const float*)d_in[3];
    const float* l1ab = (const float*)d_in[4];
    const float* l1bw = (const float*)d_in[5];
    const float* l1bb = (const float*)d_in[6];
    const float* m1w1 = (const float*)d_in[7];
    const float* m1b1 = (const float*)d_in[8];
    const float* m1w2 = (const float*)d_in[9];
    const float* m1b2 = (const float*)d_in[10];
    const float* l2aw = (const float*)d_in[11];
    const float* l2ab = (const float*)d_in[12];
    const float* l2bw = (const float*)d_in[13];
    const float* l2bb = (const float*)d_in[14];
    const float* m2w1 = (const float*)d_in[15];
    const float* m2b1 = (const float*)d_in[16];
    const float* m2w2 = (const float*)d_in[17];
    const float* m2b2 = (const float*)d_in[18];
    float* out = (float*)d_out;

    // workspace layout (4-byte units), ~450 MB
    float*  ws   = (float*)d_ws;
    __bf16* NTbf = (__bf16*)ws;                         // 50000*432 bf16
    float*  bufA = ws + 10800000;                       // 50000*112 fp32
    float*  bufC = bufA + 5600000;                      // 50000*100 fp32 (h)
    float*  W1   = bufC + 5000000;                      // 46,224
    float*  b1v  = W1 + 46224;                          // 432
    float*  W2   = b1v + 432;                           // 41,600
    float*  b2v  = W2 + 41600;                          // 416
    __bf16* Wt   = (__bf16*)(b2v + 416);                // 4*128*128 bf16
    __bf16* WT   = Wt + 65536;                          // 1344*128 bf16
    int*    off  = (int*)(WT + 172032);                 // 100,000
    int*    cur  = off + NN2;                           // 100,000
    int*    bsum = cur + NN2;                           // 512
    int*    srcp = bsum + 512;                          // 800,000
    int*    eord = srcp + NE;                           // 800,000
    __bf16* MT1  = (__bf16*)(eord + NE);                // NE*112 bf16
    __bf16* MT2  = MT1 + (size_t)NE * 112;              // NE*112 bf16
    float*  bufB = (float*)MT1;                         // t1/t2 alias (MT1 consumed)

    const int* dst = eidx + NE;

    assemble<<<256, 256, 0, stream>>>(l1aw, l1ab, l1bw, l1bb, l2aw, l2ab, l2bw, l2bb,
                                      W1, b1v, W2, b2v, Wt);
    xposeW<<<672, 256, 0, stream>>>(W1, W2, m1w1, m1w2, m2w1, m2w2, WT);

    // ---- CSR build (dst-sorted, per half; emits srcp/eord) ----
    zero_ints<<<(NN2 + 255) / 256, 256, 0, stream>>>(cur, NN2);
    count_edges<<<(NE + 255) / 256, 256, 0, stream>>>(dst, cur);
    scan_blocks<<<(NN2 + 255) / 256, 256, 0, stream>>>(cur, off, bsum, NN2);
    scan_bsum<<<1, 512, 0, stream>>>(bsum, (NN2 + 255) / 256);
    scan_add<<<(NN2 + 255) / 256, 256, 0, stream>>>(off, bsum, cur, NN2);
    scatter_edges<<<(NE + 255) / 256, 256, 0, stream>>>(eidx, cur, srcp, eord);

    // ---- all 4 edge mid-GEMMs (direct eatt gather, no ebf) ----
    mt_all<<<12500, 256, 0, stream>>>(eatt, eord, Wt, MT1, MT2);

    const int AG = NN / 4;   // 12500 blocks: 4 waves x 1 node each

    // ---- conv1 ----
    mm_bf16t<107, true><<<dim3(98, 7), 256, 0, stream>>>(x, WT, b1v, NTbf,
                                                         NN, 432, 432, 4, 0);
    edge_aggr3<107, 432><<<AG, 256, 0, stream>>>(MT1, srcp, off, NTbf, x, bufA,
                                                 0, 108, 324, 216);
    mm_bf16t<112, false><<<dim3(98, 2), 256, 0, stream>>>(bufA, WT + 896 * 128,
                                                          m1b1, bufB, NN, 100, 100, 4, 1);
    mm_bf16t<100, false><<<dim3(98, 2), 256, 0, stream>>>(bufB, WT + 1024 * 128,
                                                          m1b2, bufC, NN, 100, 100, 4, 1);

    // ---- conv2 ----  (h in bufC)
    mm_bf16t<100, true><<<dim3(98, 7), 256, 0, stream>>>(bufC, WT + 448 * 128,
                                                         b2v, NTbf, NN, 416, 416, 4, 0);
    edge_aggr3<100, 416><<<AG, 256, 0, stream>>>(MT2, srcp, off, NTbf, bufC, bufA,
                                                 0, 104, 312, 208);
    mm_bf16t<112, false><<<dim3(98, 1), 256, 0, stream>>>(bufA, WT + 1152 * 128,
                                                          m2b1, bufB, NN, 64, 64, 4, 1);
    mm_bf16t<64, false><<<dim3(98, 2), 256, 0, stream>>>(bufB, WT + 1216 * 128,
                                                         m2b2, out, NN, 100, 100, 4, 0);
}

// Round 18
// 839.063 us; speedup vs baseline: 2.7746x; 1.1586x over previous
//
#include <hip/hip_runtime.h>

// RuleGraphNet: 2x TripleConv(+mlp), N=50000 nodes, E=800000 edges.
// Pipeline: BOTH convs' edge mid-GEMMs in one dispatch (mt_both: 128-row
// tiles, direct gathered fp32 eatt input converted once into register A
// fragments and reused for conv1 AND conv2; wave-private LDS C-staging and
// copy-out, no barriers); MT1/MT2 CSR-ordered -> sequential aggregation;
// NT bf16; aggregation wave owns 1 dst node, lane owns a column pair,
// register accumulation over both phases, self fused. All dense GEMMs use
// pre-transposed bf16 weight tables.

#define NN 50000
#define NE 800000
#define EHALF 400000
#define NN2 100000
#define GB 8            // edges batched per gather group

typedef __attribute__((ext_vector_type(4))) float  f32x4;
typedef __attribute__((ext_vector_type(8))) __bf16 bf16x8;
typedef __attribute__((ext_vector_type(4))) __bf16 bf16x4;

__device__ __forceinline__ float bf16lo(unsigned u) {
    union { unsigned u; float f; } c; c.u = u << 16; return c.f;
}
__device__ __forceinline__ float bf16hi(unsigned u) {
    union { unsigned u; float f; } c; c.u = u & 0xffff0000u; return c.f;
}

// ------- generic bf16 MFMA GEMM, W from pre-transposed bf16 table ---------
template<int K, bool OBF16>
__global__ __launch_bounds__(256)
void mm_bf16t(const float* __restrict__ A, const __bf16* __restrict__ Wtt,
              const float* __restrict__ bias, void* __restrict__ Outp,
              int M, int N, int ldo, int RT, int relu)
{
    __shared__ __align__(16) __bf16 et[128 * 128];
    const int t = threadIdx.x;
    const int lane = t & 63, w = t >> 6;
    const int mh = w & 1, nh = w >> 1;
    const int l15 = lane & 15, l4 = lane >> 4;
    const int cb = blockIdx.y * 64;

    bf16x8 wf[2][4];
    const int colbase = cb + nh * 32 + l15;
    #pragma unroll
    for (int nt = 0; nt < 2; ++nt)
        #pragma unroll
        for (int ks = 0; ks < 4; ++ks)
            wf[nt][ks] = *(const bf16x8*)(Wtt + (colbase + nt * 16) * 128 +
                                          ks * 32 + l4 * 8);
    float bv[2] = {0.f, 0.f};
    if (bias) {
        #pragma unroll
        for (int nt = 0; nt < 2; ++nt) {
            int col = colbase + nt * 16;
            if (col < N) bv[nt] = bias[col];
        }
    }

    for (int it = 0; it < RT; ++it) {
        const int row0 = (blockIdx.x * RT + it) * 128;
        if (row0 >= M) break;
        __syncthreads();
        if constexpr (K % 4 == 0) {
            constexpr int QK = K / 4;
            for (int i = t; i < 128 * QK; i += 256) {
                int row = i / QK, q = i - row * QK;
                int gr = row0 + row;
                float4 v = {0.f, 0.f, 0.f, 0.f};
                if (gr < M) v = *(const float4*)(A + (size_t)gr * K + q * 4);
                bf16x4 b;
                b[0] = (__bf16)v.x; b[1] = (__bf16)v.y;
                b[2] = (__bf16)v.z; b[3] = (__bf16)v.w;
                *(bf16x4*)(et + row * 128 + ((q * 4) ^ ((row & 7) << 3))) = b;
            }
            constexpr int QP = (128 - K) / 4;
            if constexpr (QP > 0) {
                for (int i = t; i < 128 * QP; i += 256) {
                    int row = i / QP, q = QK + (i - (i / QP) * QP);
                    bf16x4 z;
                    z[0] = (__bf16)0.f; z[1] = (__bf16)0.f;
                    z[2] = (__bf16)0.f; z[3] = (__bf16)0.f;
                    *(bf16x4*)(et + row * 128 + ((q * 4) ^ ((row & 7) << 3))) = z;
                }
            }
        } else {
            for (int i = t; i < 128 * 128; i += 256) {
                int row = i >> 7, k = i & 127;
                int gr = row0 + row;
                float v = (k < K && gr < M) ? A[(size_t)gr * K + k] : 0.f;
                et[row * 128 + (k ^ ((row & 7) << 3))] = (__bf16)v;
            }
        }
        __syncthreads();

        f32x4 c[4][2] = {};
        #pragma unroll
        for (int ks = 0; ks < 4; ++ks) {
            #pragma unroll
            for (int mt = 0; mt < 4; ++mt) {
                int arow = mh * 64 + mt * 16 + l15;
                bf16x8 a = *(const bf16x8*)(et + arow * 128 +
                                            ((ks * 32 + l4 * 8) ^ ((l15 & 7) << 3)));
                c[mt][0] = __builtin_amdgcn_mfma_f32_16x16x32_bf16(a, wf[0][ks], c[mt][0], 0, 0, 0);
                c[mt][1] = __builtin_amdgcn_mfma_f32_16x16x32_bf16(a, wf[1][ks], c[mt][1], 0, 0, 0);
            }
        }

        #pragma unroll
        for (int mt = 0; mt < 4; ++mt) {
            #pragma unroll
            for (int nt = 0; nt < 2; ++nt) {
                int col = colbase + nt * 16;
                #pragma unroll
                for (int r = 0; r < 4; ++r) {
                    int row = row0 + mh * 64 + mt * 16 + l4 * 4 + r;
                    if constexpr (OBF16) {
                        if (row < M && col < ldo)
                            ((__bf16*)Outp)[(size_t)row * ldo + col] =
                                (__bf16)(c[mt][nt][r] + bv[nt]);
                    } else {
                        if (row < M && col < N) {
                            float v = c[mt][nt][r] + bv[nt];
                            if (relu) v = fmaxf(v, 0.f);
                            ((float*)Outp)[(size_t)row * ldo + col] = v;
                        }
                    }
                }
            }
        }
    }
}

// ---------------- CSR build (edges sorted by dst, per half) ----------------
__global__ void zero_ints(int* __restrict__ p, int n)
{
    int i = blockIdx.x * 256 + threadIdx.x;
    if (i < n) p[i] = 0;
}

__global__ void count_edges(const int* __restrict__ dst, int* __restrict__ cnt)
{
    int e = blockIdx.x * 256 + threadIdx.x;
    if (e < NE) atomicAdd(&cnt[dst[e] + (e >= EHALF ? NN : 0)], 1);
}

__global__ void scan_blocks(const int* __restrict__ cnt, int* __restrict__ off,
                            int* __restrict__ bsum, int n)
{
    __shared__ int s[256];
    int t = threadIdx.x, g = blockIdx.x * 256 + t;
    int v = (g < n) ? cnt[g] : 0;
    s[t] = v; __syncthreads();
    for (int d = 1; d < 256; d <<= 1) {
        int add = (t >= d) ? s[t - d] : 0;
        __syncthreads();
        s[t] += add;
        __syncthreads();
    }
    if (g < n) off[g] = s[t] - v;
    if (t == 255) bsum[blockIdx.x] = s[255];
}

__global__ void scan_bsum(int* __restrict__ bsum, int nb)
{
    __shared__ int s[512];
    int t = threadIdx.x;
    int v = (t < nb) ? bsum[t] : 0;
    s[t] = v; __syncthreads();
    for (int d = 1; d < 512; d <<= 1) {
        int add = (t >= d) ? s[t - d] : 0;
        __syncthreads();
        s[t] += add;
        __syncthreads();
    }
    if (t < nb) bsum[t] = s[t] - v;
}

__global__ void scan_add(int* __restrict__ off, const int* __restrict__ bsum,
                         int* __restrict__ cur, int n)
{
    int g = blockIdx.x * 256 + threadIdx.x;
    if (g < n) { int o = off[g] + bsum[blockIdx.x]; off[g] = o; cur[g] = o; }
}

__global__ void scatter_edges(const int* __restrict__ eidx, int* __restrict__ cur,
                              int* __restrict__ srcp, int* __restrict__ eord)
{
    int e = blockIdx.x * 256 + threadIdx.x;
    if (e < NE) {
        int s = eidx[e], d = eidx[NE + e];
        int pos = atomicAdd(&cur[d + (e >= EHALF ? NN : 0)], 1);
        srcp[pos] = s;
        eord[pos] = e;
    }
}

// ----- mt_both: both convs' edge mid-GEMMs, A fragments gathered once -----
// grid 6250: block owns 128 CSR rows; half = rows<EHALF ? a : b. A-fragments
// gathered from fp32 eatt (eord indirection) + converted bf16 ONCE into
// registers, reused for conv1 and conv2 (W quarters half and 2+half). C
// staged in LDS (stride 116, conflict-free); wave-private copy-out, no
// barriers (ct regions are wave-private; in-wave LDS ordering via lgkmcnt).
__global__ __launch_bounds__(256)
void mt_both(const float* __restrict__ eatt,   // [NE][100] original order
             const int* __restrict__ eord,     // [NE] CSR pos -> edge id
             const __bf16* __restrict__ Wt,    // [4][128][128]
             __bf16* __restrict__ MT1,         // [NE][112] CSR order
             __bf16* __restrict__ MT2)         // [NE][112] CSR order
{
    __shared__ __align__(16) __bf16 ct[128 * 116];   // 29.7 KB
    const int t = threadIdx.x;
    const int lane = t & 63, w = t >> 6;
    const int mh = w & 1, nq = w >> 1;
    const int l15 = lane & 15, l4 = lane >> 4;
    const size_t row0 = (size_t)blockIdx.x * 128;
    const int half = (row0 >= EHALF) ? 1 : 0;
    const int colbase = nq * 64 + l15;
    const int rbase = mh * 64;

    // A fragments gathered + converted once (reused for both convs)
    bf16x8 af[4][4];
    {
        const float* ep[4];
        #pragma unroll
        for (int mt = 0; mt < 4; ++mt) {
            size_t row = row0 + mh * 64 + mt * 16 + l15;
            ep[mt] = eatt + (size_t)eord[row] * 100;
        }
        #pragma unroll
        for (int ks = 0; ks < 4; ++ks) {
            const int bk = ks * 32 + l4 * 8;
            #pragma unroll
            for (int mt = 0; mt < 4; ++mt) {
                float4 v0 = {0.f, 0.f, 0.f, 0.f}, v1 = {0.f, 0.f, 0.f, 0.f};
                if (bk < 100)     v0 = *(const float4*)(ep[mt] + bk);
                if (bk + 4 < 100) v1 = *(const float4*)(ep[mt] + bk + 4);
                bf16x8 a;
                a[0] = (__bf16)v0.x; a[1] = (__bf16)v0.y;
                a[2] = (__bf16)v0.z; a[3] = (__bf16)v0.w;
                a[4] = (__bf16)v1.x; a[5] = (__bf16)v1.y;
                a[6] = (__bf16)v1.z; a[7] = (__bf16)v1.w;
                af[mt][ks] = a;
            }
        }
    }

    #pragma unroll
    for (int conv = 0; conv < 2; ++conv) {
        const __bf16* Wq = Wt + (size_t)(conv * 2 + half) * 16384;
        __bf16* MT = conv ? MT2 : MT1;

        bf16x8 wf[4][4];
        #pragma unroll
        for (int nt = 0; nt < 4; ++nt)
            #pragma unroll
            for (int ks = 0; ks < 4; ++ks)
                wf[nt][ks] = *(const bf16x8*)(Wq + (colbase + nt * 16) * 128 +
                                              ks * 32 + l4 * 8);

        f32x4 c[4][4] = {};
        #pragma unroll
        for (int ks = 0; ks < 4; ++ks)
            #pragma unroll
            for (int mt = 0; mt < 4; ++mt)
                #pragma unroll
                for (int nt = 0; nt < 4; ++nt)
                    c[mt][nt] = __builtin_amdgcn_mfma_f32_16x16x32_bf16(
                        af[mt][ks], wf[nt][ks], c[mt][nt], 0, 0, 0);

        #pragma unroll
        for (int mt = 0; mt < 4; ++mt) {
            #pragma unroll
            for (int nt = 0; nt < 4; ++nt) {
                int col = colbase + nt * 16;
                if (col < 112) {
                    #pragma unroll
                    for (int r = 0; r < 4; ++r) {
                        int lrow = mh * 64 + mt * 16 + l4 * 4 + r;
                        ct[lrow * 116 + col] = (__bf16)c[mt][nt][r];
                    }
                }
            }
        }
        // wave-private copy-out: rows [mh*64,+64), cols nq? 64..111 : 0..63
        __bf16* gout = MT + (row0 + rbase) * 112;
        if (nq == 0) {
            #pragma unroll
            for (int k = 0; k < 16; ++k) {
                int i = lane + 64 * k;
                int row = i >> 4, ch = i & 15;
                *(uint2*)(gout + row * 112 + ch * 4) =
                    *(const uint2*)(ct + (rbase + row) * 116 + ch * 4);
            }
        } else {
            #pragma unroll
            for (int k = 0; k < 12; ++k) {
                int i = lane + 64 * k;
                int row = i / 12, ch = i - row * 12;
                *(uint2*)(gout + row * 112 + 64 + ch * 4) =
                    *(const uint2*)(ct + (rbase + row) * 116 + 64 + ch * 4);
            }
        }
    }
}

// ---------------- edge_aggr3: both phases, register accumulation ----------
template<int ND, int NTS>
__global__ __launch_bounds__(256)
void edge_aggr3(const __bf16* __restrict__ MT,    // [NE][112] CSR order
                const int* __restrict__ srcp,     // [NE] src per CSR position
                const int* __restrict__ off,      // [NN2]
                const __bf16* __restrict__ NT,    // [NN][NTS] bf16
                const float* __restrict__ self,   // [NN][ND] fp32
                float* __restrict__ aggr,         // [NN][112]
                int blkd0, int blks0, int blkd1, int blks1)
{
    const int t = threadIdx.x;
    const int lane = t & 63, wv = t >> 6;
    const int c0 = lane * 2;
    const bool a0 = c0 < ND, a1 = c0 + 1 < ND;
    const int n = blockIdx.x * 4 + wv;     // one node per wave

    float acc0 = 0.f, acc1 = 0.f;

    #pragma unroll
    for (int phase = 0; phase < 2; ++phase) {
        const int blkd = phase ? blkd1 : blkd0;
        const int blks = phase ? blks1 : blks0;
        const int idx = phase * NN + n;
        const int pb = off[idx];
        const int pe = (idx + 1 == NN2) ? NE : off[idx + 1];

        float nd0 = 0.f, nd1 = 0.f;
        if (a0) {
            unsigned nd = *(const unsigned*)(NT + (size_t)n * NTS + blkd + c0);
            nd0 = bf16lo(nd); nd1 = bf16hi(nd);
        }

        for (int p = pb; p < pe; p += GB) {
            int ok[GB], ss[GB];
            #pragma unroll
            for (int i = 0; i < GB; ++i) {
                int pp = p + i;
                ok[i] = pp < pe;
                ss[i] = ok[i] ? srcp[pp] : 0;
            }
            unsigned mtw[GB], nsw[GB];
            #pragma unroll
            for (int i = 0; i < GB; ++i) {
                mtw[i] = 0u; nsw[i] = 0u;
                if (ok[i] && a0) {
                    mtw[i] = *(const unsigned*)(MT + (size_t)(p + i) * 112 + c0);
                    nsw[i] = *(const unsigned*)(NT + (size_t)ss[i] * NTS + blks + c0);
                }
            }
            #pragma unroll
            for (int i = 0; i < GB; ++i) {
                if (!ok[i]) continue;             // wave-uniform
                acc0 += fmaxf(bf16lo(mtw[i]) + nd0 + bf16lo(nsw[i]), 0.f);
                acc1 += fmaxf(bf16hi(mtw[i]) + nd1 + bf16hi(nsw[i]), 0.f);
            }
        }
    }

    if (c0 < 112) {
        const size_t g0 = (size_t)n * 112 + c0;
        aggr[g0]     = a0 ? (acc0 + self[(size_t)n * ND + c0])     : 0.f;
        aggr[g0 + 1] = a1 ? (acc1 + self[(size_t)n * ND + c0 + 1]) : 0.f;
    }
}

// ---- weight assembly: padded concat blocks + transposed mid blocks -------
__global__ void assemble(const float* __restrict__ l1a, const float* __restrict__ l1ab,
                         const float* __restrict__ l1b, const float* __restrict__ l1bb,
                         const float* __restrict__ l2a, const float* __restrict__ l2ab,
                         const float* __restrict__ l2b, const float* __restrict__ l2bb,
                         float* __restrict__ W1, float* __restrict__ b1,
                         float* __restrict__ W2, float* __restrict__ b2,
                         __bf16* __restrict__ Wt)
{
    int i = blockIdx.x * 256 + threadIdx.x;
    if (i < 107 * 432) {
        int k = i / 432, c = i % 432;
        int q = c / 108, cc = c - q * 108;
        float v = 0.f;
        if (cc < 107) {
            if (q == 0)      v = l1a[k * 107 + cc];
            else if (q == 1) v = l1a[(207 + k) * 107 + cc];
            else if (q == 2) v = l1b[k * 107 + cc];
            else             v = l1b[(207 + k) * 107 + cc];
        }
        W1[i] = v;
    }
    if (i < 432) {
        int q = i / 108, cc = i - q * 108;
        b1[i] = (cc < 107) ? (q == 0 ? l1ab[cc] : (q == 3 ? l1bb[cc] : 0.f)) : 0.f;
    }
    if (i < 100 * 416) {
        int k = i / 416, c = i % 416;
        int q = c / 104, cc = c - q * 104;
        float v = 0.f;
        if (cc < 100) {
            if (q == 0)      v = l2a[k * 100 + cc];
            else if (q == 1) v = l2a[(200 + k) * 100 + cc];
            else if (q == 2) v = l2b[k * 100 + cc];
            else             v = l2b[(200 + k) * 100 + cc];
        }
        W2[i] = v;
    }
    if (i < 416) {
        int q = i / 104, cc = i - q * 104;
        b2[i] = (cc < 100) ? (q == 0 ? l2ab[cc] : (q == 3 ? l2bb[cc] : 0.f)) : 0.f;
    }
    if (i < 4 * 128 * 128) {
        int q = i >> 14, col = (i >> 7) & 127, k = i & 127;
        const float* Wm = (q == 0) ? l1a + 107 * 107 :
                          (q == 1) ? l1b + 107 * 107 :
                          (q == 2) ? l2a + 100 * 100 : l2b + 100 * 100;
        int ND = (q < 2) ? 107 : 100;
        float v = (k < 100 && col < ND) ? Wm[k * ND + col] : 0.f;
        Wt[i] = (__bf16)v;
    }
}

// ---- xposeW: transpose all dense-GEMM weights into bf16 [1344][128] ------
__global__ __launch_bounds__(256)
void xposeW(const float* __restrict__ W1, const float* __restrict__ W2,
            const float* __restrict__ m1w1, const float* __restrict__ m1w2,
            const float* __restrict__ m2w1, const float* __restrict__ m2w2,
            __bf16* __restrict__ WT)
{
    int i = blockIdx.x * 256 + threadIdx.x;
    if (i >= 1344 * 128) return;
    int c = i >> 7, k = i & 127;
    const float* src; int lc, cr, K, st;
    if (c < 448)      { src = W1;   lc = c;        cr = 432; K = 107; st = 432; }
    else if (c < 896) { src = W2;   lc = c - 448;  cr = 416; K = 100; st = 416; }
    else if (c < 1024){ src = m1w1; lc = c - 896;  cr = 100; K = 107; st = 100; }
    else if (c < 1152){ src = m1w2; lc = c - 1024; cr = 100; K = 100; st = 100; }
    else if (c < 1216){ src = m2w1; lc = c - 1152; cr = 64;  K = 100; st = 64;  }
    else              { src = m2w2; lc = c - 1216; cr = 100; K = 64;  st = 100; }
    float v = (lc < cr && k < K) ? src[k * st + lc] : 0.f;
    WT[i] = (__bf16)v;
}

extern "C" void kernel_launch(void* const* d_in, const int* in_sizes, int n_in,
                              void* d_out, int out_size, void* d_ws, size_t ws_size,
                              hipStream_t stream)
{
    const float* x    = (const float*)d_in[0];
    const int*   eidx = (const int*)d_in[1];
    const float* eatt = (const float*)d_in[2];
    const float* l1aw = (const float*)d_in[3];
    const float* l1ab = (const float*)d_in[4];
    const float* l1bw = (const float*)d_in[5];
    const float* l1bb = (const float*)d_in[6];
    const float* m1w1 = (const float*)d_in[7];
    const float* m1b1 = (const float*)d_in[8];
    const float* m1w2 = (const float*)d_in[9];
    const float* m1b2 = (const float*)d_in[10];
    const float* l2aw = (const float*)d_in[11];
    const float* l2ab = (const float*)d_in[12];
    const float* l2bw = (const float*)d_in[13];
    const float* l2bb = (const float*)d_in[14];
    const float* m2w1 = (const float*)d_in[15];
    const float* m2b1 = (const float*)d_in[16];
    const float* m2w2 = (const float*)d_in[17];
    const float* m2b2 = (const float*)d_in[18];
    float* out = (float*)d_out;

    // workspace layout (4-byte units), ~450 MB
    float*  ws   = (float*)d_ws;
    __bf16* NTbf = (__bf16*)ws;                         // 50000*432 bf16
    float*  bufA = ws + 10800000;                       // 50000*112 fp32
    float*  bufC = bufA + 5600000;                      // 50000*100 fp32 (h)
    float*  W1   = bufC + 5000000;                      // 46,224
    float*  b1v  = W1 + 46224;                          // 432
    float*  W2   = b1v + 432;                           // 41,600
    float*  b2v  = W2 + 41600;                          // 416
    __bf16* Wt   = (__bf16*)(b2v + 416);                // 4*128*128 bf16
    __bf16* WT   = Wt + 65536;                          // 1344*128 bf16
    int*    off  = (int*)(WT + 172032);                 // 100,000
    int*    cur  = off + NN2;                           // 100,000
    int*    bsum = cur + NN2;                           // 512
    int*    srcp = bsum + 512;                          // 800,000
    int*    eord = srcp + NE;                           // 800,000
    __bf16* MT1  = (__bf16*)(eord + NE);                // NE*112 bf16
    __bf16* MT2  = MT1 + (size_t)NE * 112;              // NE*112 bf16
    float*  bufB = (float*)MT1;                         // t1/t2 alias (MT1 consumed)

    const int* dst = eidx + NE;

    assemble<<<256, 256, 0, stream>>>(l1aw, l1ab, l1bw, l1bb, l2aw, l2ab, l2bw, l2bb,
                                      W1, b1v, W2, b2v, Wt);
    xposeW<<<672, 256, 0, stream>>>(W1, W2, m1w1, m1w2, m2w1, m2w2, WT);

    // ---- CSR build (dst-sorted, per half; emits srcp/eord) ----
    zero_ints<<<(NN2 + 255) / 256, 256, 0, stream>>>(cur, NN2);
    count_edges<<<(NE + 255) / 256, 256, 0, stream>>>(dst, cur);
    scan_blocks<<<(NN2 + 255) / 256, 256, 0, stream>>>(cur, off, bsum, NN2);
    scan_bsum<<<1, 512, 0, stream>>>(bsum, (NN2 + 255) / 256);
    scan_add<<<(NN2 + 255) / 256, 256, 0, stream>>>(off, bsum, cur, NN2);
    scatter_edges<<<(NE + 255) / 256, 256, 0, stream>>>(eidx, cur, srcp, eord);

    // ---- both convs' edge mid-GEMMs (A gathered once, reused) ----
    mt_both<<<6250, 256, 0, stream>>>(eatt, eord, Wt, MT1, MT2);

    const int AG = NN / 4;   // 12500 blocks: 4 waves x 1 node each

    // ---- conv1 ----
    mm_bf16t<107, true><<<dim3(98, 7), 256, 0, stream>>>(x, WT, b1v, NTbf,
                                                         NN, 432, 432, 4, 0);
    edge_aggr3<107, 432><<<AG, 256, 0, stream>>>(MT1, srcp, off, NTbf, x, bufA,
                                                 0, 108, 324, 216);
    mm_bf16t<112, false><<<dim3(98, 2), 256, 0, stream>>>(bufA, WT + 896 * 128,
                                                          m1b1, bufB, NN, 100, 100, 4, 1);
    mm_bf16t<100, false><<<dim3(98, 2), 256, 0, stream>>>(bufB, WT + 1024 * 128,
                                                          m1b2, bufC, NN, 100, 100, 4, 1);

    // ---- conv2 ----  (h in bufC)
    mm_bf16t<100, true><<<dim3(98, 7), 256, 0, stream>>>(bufC, WT + 448 * 128,
                                                         b2v, NTbf, NN, 416, 416, 4, 0);
    edge_aggr3<100, 416><<<AG, 256, 0, stream>>>(MT2, srcp, off, NTbf, bufC, bufA,
                                                 0, 104, 312, 208);
    mm_bf16t<112, false><<<dim3(98, 1), 256, 0, stream>>>(bufA, WT + 1152 * 128,
                                                          m2b1, bufB, NN, 64, 64, 4, 1);
    mm_bf16t<64, false><<<dim3(98, 2), 256, 0, stream>>>(bufB, WT + 1216 * 128,
                                                         m2b2, out, NN, 100, 100, 4, 0);
}

// Round 19
// 761.567 us; speedup vs baseline: 3.0569x; 1.1018x over previous
//
#include <hip/hip_runtime.h>

// RuleGraphNet: 2x TripleConv(+mlp), N=50000 nodes, E=800000 edges.
// Pipeline: BOTH convs' edge mid-GEMMs in one dispatch (mt_both: 128-row
// tiles, direct gathered fp32 eatt input converted once into register A
// fragments reused for conv1 AND conv2; per-n-quad W/C register blocking to
// keep VGPR low; wave-private LDS C-staging + copy-out, no barriers);
// MT1/MT2 CSR-ordered -> sequential aggregation; NT bf16; aggregation wave
// owns 1 dst node, lane owns a column pair, register accumulation over both
// phases, self fused. All dense GEMMs use pre-transposed bf16 weight tables
// and single-tile blocks (RT=1) for maximum block-level parallelism.

#define NN 50000
#define NE 800000
#define EHALF 400000
#define NN2 100000
#define GB 8            // edges batched per gather group

typedef __attribute__((ext_vector_type(4))) float  f32x4;
typedef __attribute__((ext_vector_type(8))) __bf16 bf16x8;
typedef __attribute__((ext_vector_type(4))) __bf16 bf16x4;

__device__ __forceinline__ float bf16lo(unsigned u) {
    union { unsigned u; float f; } c; c.u = u << 16; return c.f;
}
__device__ __forceinline__ float bf16hi(unsigned u) {
    union { unsigned u; float f; } c; c.u = u & 0xffff0000u; return c.f;
}

// ------- generic bf16 MFMA GEMM, W from pre-transposed bf16 table ---------
template<int K, bool OBF16>
__global__ __launch_bounds__(256)
void mm_bf16t(const float* __restrict__ A, const __bf16* __restrict__ Wtt,
              const float* __restrict__ bias, void* __restrict__ Outp,
              int M, int N, int ldo, int RT, int relu)
{
    __shared__ __align__(16) __bf16 et[128 * 128];
    const int t = threadIdx.x;
    const int lane = t & 63, w = t >> 6;
    const int mh = w & 1, nh = w >> 1;
    const int l15 = lane & 15, l4 = lane >> 4;
    const int cb = blockIdx.y * 64;

    bf16x8 wf[2][4];
    const int colbase = cb + nh * 32 + l15;
    #pragma unroll
    for (int nt = 0; nt < 2; ++nt)
        #pragma unroll
        for (int ks = 0; ks < 4; ++ks)
            wf[nt][ks] = *(const bf16x8*)(Wtt + (colbase + nt * 16) * 128 +
                                          ks * 32 + l4 * 8);
    float bv[2] = {0.f, 0.f};
    if (bias) {
        #pragma unroll
        for (int nt = 0; nt < 2; ++nt) {
            int col = colbase + nt * 16;
            if (col < N) bv[nt] = bias[col];
        }
    }

    for (int it = 0; it < RT; ++it) {
        const int row0 = (blockIdx.x * RT + it) * 128;
        if (row0 >= M) break;
        __syncthreads();
        if constexpr (K % 4 == 0) {
            constexpr int QK = K / 4;
            for (int i = t; i < 128 * QK; i += 256) {
                int row = i / QK, q = i - row * QK;
                int gr = row0 + row;
                float4 v = {0.f, 0.f, 0.f, 0.f};
                if (gr < M) v = *(const float4*)(A + (size_t)gr * K + q * 4);
                bf16x4 b;
                b[0] = (__bf16)v.x; b[1] = (__bf16)v.y;
                b[2] = (__bf16)v.z; b[3] = (__bf16)v.w;
                *(bf16x4*)(et + row * 128 + ((q * 4) ^ ((row & 7) << 3))) = b;
            }
            constexpr int QP = (128 - K) / 4;
            if constexpr (QP > 0) {
                for (int i = t; i < 128 * QP; i += 256) {
                    int row = i / QP, q = QK + (i - (i / QP) * QP);
                    bf16x4 z;
                    z[0] = (__bf16)0.f; z[1] = (__bf16)0.f;
                    z[2] = (__bf16)0.f; z[3] = (__bf16)0.f;
                    *(bf16x4*)(et + row * 128 + ((q * 4) ^ ((row & 7) << 3))) = z;
                }
            }
        } else {
            for (int i = t; i < 128 * 128; i += 256) {
                int row = i >> 7, k = i & 127;
                int gr = row0 + row;
                float v = (k < K && gr < M) ? A[(size_t)gr * K + k] : 0.f;
                et[row * 128 + (k ^ ((row & 7) << 3))] = (__bf16)v;
            }
        }
        __syncthreads();

        f32x4 c[4][2] = {};
        #pragma unroll
        for (int ks = 0; ks < 4; ++ks) {
            #pragma unroll
            for (int mt = 0; mt < 4; ++mt) {
                int arow = mh * 64 + mt * 16 + l15;
                bf16x8 a = *(const bf16x8*)(et + arow * 128 +
                                            ((ks * 32 + l4 * 8) ^ ((l15 & 7) << 3)));
                c[mt][0] = __builtin_amdgcn_mfma_f32_16x16x32_bf16(a, wf[0][ks], c[mt][0], 0, 0, 0);
                c[mt][1] = __builtin_amdgcn_mfma_f32_16x16x32_bf16(a, wf[1][ks], c[mt][1], 0, 0, 0);
            }
        }

        #pragma unroll
        for (int mt = 0; mt < 4; ++mt) {
            #pragma unroll
            for (int nt = 0; nt < 2; ++nt) {
                int col = colbase + nt * 16;
                #pragma unroll
                for (int r = 0; r < 4; ++r) {
                    int row = row0 + mh * 64 + mt * 16 + l4 * 4 + r;
                    if constexpr (OBF16) {
                        if (row < M && col < ldo)
                            ((__bf16*)Outp)[(size_t)row * ldo + col] =
                                (__bf16)(c[mt][nt][r] + bv[nt]);
                    } else {
                        if (row < M && col < N) {
                            float v = c[mt][nt][r] + bv[nt];
                            if (relu) v = fmaxf(v, 0.f);
                            ((float*)Outp)[(size_t)row * ldo + col] = v;
                        }
                    }
                }
            }
        }
    }
}

// ---------------- CSR build (edges sorted by dst, per half) ----------------
__global__ void zero_ints(int* __restrict__ p, int n)
{
    int i = blockIdx.x * 256 + threadIdx.x;
    if (i < n) p[i] = 0;
}

__global__ void count_edges(const int* __restrict__ dst, int* __restrict__ cnt)
{
    int e = blockIdx.x * 256 + threadIdx.x;
    if (e < NE) atomicAdd(&cnt[dst[e] + (e >= EHALF ? NN : 0)], 1);
}

__global__ void scan_blocks(const int* __restrict__ cnt, int* __restrict__ off,
                            int* __restrict__ bsum, int n)
{
    __shared__ int s[256];
    int t = threadIdx.x, g = blockIdx.x * 256 + t;
    int v = (g < n) ? cnt[g] : 0;
    s[t] = v; __syncthreads();
    for (int d = 1; d < 256; d <<= 1) {
        int add = (t >= d) ? s[t - d] : 0;
        __syncthreads();
        s[t] += add;
        __syncthreads();
    }
    if (g < n) off[g] = s[t] - v;
    if (t == 255) bsum[blockIdx.x] = s[255];
}

__global__ void scan_bsum(int* __restrict__ bsum, int nb)
{
    __shared__ int s[512];
    int t = threadIdx.x;
    int v = (t < nb) ? bsum[t] : 0;
    s[t] = v; __syncthreads();
    for (int d = 1; d < 512; d <<= 1) {
        int add = (t >= d) ? s[t - d] : 0;
        __syncthreads();
        s[t] += add;
        __syncthreads();
    }
    if (t < nb) bsum[t] = s[t] - v;
}

__global__ void scan_add(int* __restrict__ off, const int* __restrict__ bsum,
                         int* __restrict__ cur, int n)
{
    int g = blockIdx.x * 256 + threadIdx.x;
    if (g < n) { int o = off[g] + bsum[blockIdx.x]; off[g] = o; cur[g] = o; }
}

__global__ void scatter_edges(const int* __restrict__ eidx, int* __restrict__ cur,
                              int* __restrict__ srcp, int* __restrict__ eord)
{
    int e = blockIdx.x * 256 + threadIdx.x;
    if (e < NE) {
        int s = eidx[e], d = eidx[NE + e];
        int pos = atomicAdd(&cur[d + (e >= EHALF ? NN : 0)], 1);
        srcp[pos] = s;
        eord[pos] = e;
    }
}

// ----- mt_both: both convs' edge mid-GEMMs, A fragments gathered once -----
// grid 6250: block owns 128 CSR rows; half = rows<EHALF ? a : b. A-fragments
// gathered from fp32 eatt (eord indirection) + converted bf16 ONCE into
// registers, reused for conv1 and conv2. Per-n-quad register blocking (wfn[4]
// + c4[4] live at a time, nt loop not unrolled) keeps VGPR low for occupancy.
// C staged in LDS (stride 116, conflict-free); wave-private copy-out.
__global__ __launch_bounds__(256)
void mt_both(const float* __restrict__ eatt,   // [NE][100] original order
             const int* __restrict__ eord,     // [NE] CSR pos -> edge id
             const __bf16* __restrict__ Wt,    // [4][128][128]
             __bf16* __restrict__ MT1,         // [NE][112] CSR order
             __bf16* __restrict__ MT2)         // [NE][112] CSR order
{
    __shared__ __align__(16) __bf16 ct[128 * 116];   // 29.7 KB
    const int t = threadIdx.x;
    const int lane = t & 63, w = t >> 6;
    const int mh = w & 1, nq = w >> 1;
    const int l15 = lane & 15, l4 = lane >> 4;
    const size_t row0 = (size_t)blockIdx.x * 128;
    const int half = (row0 >= EHALF) ? 1 : 0;
    const int colbase = nq * 64 + l15;
    const int rbase = mh * 64;

    // A fragments gathered + converted once (reused for both convs)
    bf16x8 af[4][4];
    {
        const float* ep[4];
        #pragma unroll
        for (int mt = 0; mt < 4; ++mt) {
            size_t row = row0 + mh * 64 + mt * 16 + l15;
            ep[mt] = eatt + (size_t)eord[row] * 100;
        }
        #pragma unroll
        for (int ks = 0; ks < 4; ++ks) {
            const int bk = ks * 32 + l4 * 8;
            #pragma unroll
            for (int mt = 0; mt < 4; ++mt) {
                float4 v0 = {0.f, 0.f, 0.f, 0.f}, v1 = {0.f, 0.f, 0.f, 0.f};
                if (bk < 100)     v0 = *(const float4*)(ep[mt] + bk);
                if (bk + 4 < 100) v1 = *(const float4*)(ep[mt] + bk + 4);
                bf16x8 a;
                a[0] = (__bf16)v0.x; a[1] = (__bf16)v0.y;
                a[2] = (__bf16)v0.z; a[3] = (__bf16)v0.w;
                a[4] = (__bf16)v1.x; a[5] = (__bf16)v1.y;
                a[6] = (__bf16)v1.z; a[7] = (__bf16)v1.w;
                af[mt][ks] = a;
            }
        }
    }

    #pragma unroll 1
    for (int conv = 0; conv < 2; ++conv) {
        const __bf16* Wq = Wt + (size_t)(conv * 2 + half) * 16384;
        __bf16* MT = conv ? MT2 : MT1;

        #pragma unroll 1
        for (int nt = 0; nt < 4; ++nt) {
            const int col = colbase + nt * 16;
            bf16x8 wfn[4];
            #pragma unroll
            for (int ks = 0; ks < 4; ++ks)
                wfn[ks] = *(const bf16x8*)(Wq + col * 128 + ks * 32 + l4 * 8);
            f32x4 c4[4] = {};
            #pragma unroll
            for (int ks = 0; ks < 4; ++ks)
                #pragma unroll
                for (int mt = 0; mt < 4; ++mt)
                    c4[mt] = __builtin_amdgcn_mfma_f32_16x16x32_bf16(
                        af[mt][ks], wfn[ks], c4[mt], 0, 0, 0);
            if (col < 112) {
                #pragma unroll
                for (int mt = 0; mt < 4; ++mt)
                    #pragma unroll
                    for (int r = 0; r < 4; ++r)
                        ct[(mh * 64 + mt * 16 + l4 * 4 + r) * 116 + col] =
                            (__bf16)c4[mt][r];
            }
        }

        // wave-private copy-out: rows [mh*64,+64), cols nq? 64..111 : 0..63
        __bf16* gout = MT + (row0 + rbase) * 112;
        if (nq == 0) {
            #pragma unroll
            for (int k = 0; k < 16; ++k) {
                int i = lane + 64 * k;
                int row = i >> 4, ch = i & 15;
                *(uint2*)(gout + row * 112 + ch * 4) =
                    *(const uint2*)(ct + (rbase + row) * 116 + ch * 4);
            }
        } else {
            #pragma unroll
            for (int k = 0; k < 12; ++k) {
                int i = lane + 64 * k;
                int row = i / 12, ch = i - row * 12;
                *(uint2*)(gout + row * 112 + 64 + ch * 4) =
                    *(const uint2*)(ct + (rbase + row) * 116 + 64 + ch * 4);
            }
        }
    }
}

// ---------------- edge_aggr3: both phases, register accumulation ----------
template<int ND, int NTS>
__global__ __launch_bounds__(256)
void edge_aggr3(const __bf16* __restrict__ MT,    // [NE][112] CSR order
                const int* __restrict__ srcp,     // [NE] src per CSR position
                const int* __restrict__ off,      // [NN2]
                const __bf16* __restrict__ NT,    // [NN][NTS] bf16
                const float* __restrict__ self,   // [NN][ND] fp32
                float* __restrict__ aggr,         // [NN][112]
                int blkd0, int blks0, int blkd1, int blks1)
{
    const int t = threadIdx.x;
    const int lane = t & 63, wv = t >> 6;
    const int c0 = lane * 2;
    const bool a0 = c0 < ND, a1 = c0 + 1 < ND;
    const int n = blockIdx.x * 4 + wv;     // one node per wave

    float acc0 = 0.f, acc1 = 0.f;

    #pragma unroll
    for (int phase = 0; phase < 2; ++phase) {
        const int blkd = phase ? blkd1 : blkd0;
        const int blks = phase ? blks1 : blks0;
        const int idx = phase * NN + n;
        const int pb = off[idx];
        const int pe = (idx + 1 == NN2) ? NE : off[idx + 1];

        float nd0 = 0.f, nd1 = 0.f;
        if (a0) {
            unsigned nd = *(const unsigned*)(NT + (size_t)n * NTS + blkd + c0);
            nd0 = bf16lo(nd); nd1 = bf16hi(nd);
        }

        for (int p = pb; p < pe; p += GB) {
            int ok[GB], ss[GB];
            #pragma unroll
            for (int i = 0; i < GB; ++i) {
                int pp = p + i;
                ok[i] = pp < pe;
                ss[i] = ok[i] ? srcp[pp] : 0;
            }
            unsigned mtw[GB], nsw[GB];
            #pragma unroll
            for (int i = 0; i < GB; ++i) {
                mtw[i] = 0u; nsw[i] = 0u;
                if (ok[i] && a0) {
                    mtw[i] = *(const unsigned*)(MT + (size_t)(p + i) * 112 + c0);
                    nsw[i] = *(const unsigned*)(NT + (size_t)ss[i] * NTS + blks + c0);
                }
            }
            #pragma unroll
            for (int i = 0; i < GB; ++i) {
                if (!ok[i]) continue;             // wave-uniform
                acc0 += fmaxf(bf16lo(mtw[i]) + nd0 + bf16lo(nsw[i]), 0.f);
                acc1 += fmaxf(bf16hi(mtw[i]) + nd1 + bf16hi(nsw[i]), 0.f);
            }
        }
    }

    if (c0 < 112) {
        const size_t g0 = (size_t)n * 112 + c0;
        aggr[g0]     = a0 ? (acc0 + self[(size_t)n * ND + c0])     : 0.f;
        aggr[g0 + 1] = a1 ? (acc1 + self[(size_t)n * ND + c0 + 1]) : 0.f;
    }
}

// ---- weight assembly: padded concat blocks + transposed mid blocks -------
__global__ void assemble(const float* __restrict__ l1a, const float* __restrict__ l1ab,
                         const float* __restrict__ l1b, const float* __restrict__ l1bb,
                         const float* __restrict__ l2a, const float* __restrict__ l2ab,
                         const float* __restrict__ l2b, const float* __restrict__ l2bb,
                         float* __restrict__ W1, float* __restrict__ b1,
                         float* __restrict__ W2, float* __restrict__ b2,
                         __bf16* __restrict__ Wt)
{
    int i = blockIdx.x * 256 + threadIdx.x;
    if (i < 107 * 432) {
        int k = i / 432, c = i % 432;
        int q = c / 108, cc = c - q * 108;
        float v = 0.f;
        if (cc < 107) {
            if (q == 0)      v = l1a[k * 107 + cc];
            else if (q == 1) v = l1a[(207 + k) * 107 + cc];
            else if (q == 2) v = l1b[k * 107 + cc];
            else             v = l1b[(207 + k) * 107 + cc];
        }
        W1[i] = v;
    }
    if (i < 432) {
        int q = i / 108, cc = i - q * 108;
        b1[i] = (cc < 107) ? (q == 0 ? l1ab[cc] : (q == 3 ? l1bb[cc] : 0.f)) : 0.f;
    }
    if (i < 100 * 416) {
        int k = i / 416, c = i % 416;
        int q = c / 104, cc = c - q * 104;
        float v = 0.f;
        if (cc < 100) {
            if (q == 0)      v = l2a[k * 100 + cc];
            else if (q == 1) v = l2a[(200 + k) * 100 + cc];
            else if (q == 2) v = l2b[k * 100 + cc];
            else             v = l2b[(200 + k) * 100 + cc];
        }
        W2[i] = v;
    }
    if (i < 416) {
        int q = i / 104, cc = i - q * 104;
        b2[i] = (cc < 100) ? (q == 0 ? l2ab[cc] : (q == 3 ? l2bb[cc] : 0.f)) : 0.f;
    }
    if (i < 4 * 128 * 128) {
        int q = i >> 14, col = (i >> 7) & 127, k = i & 127;
        const float* Wm = (q == 0) ? l1a + 107 * 107 :
                          (q == 1) ? l1b + 107 * 107 :
                          (q == 2) ? l2a + 100 * 100 : l2b + 100 * 100;
        int ND = (q < 2) ? 107 : 100;
        float v = (k < 100 && col < ND) ? Wm[k * ND + col] : 0.f;
        Wt[i] = (__bf16)v;
    }
}

// ---- xposeW: transpose all dense-GEMM weights into bf16 [1344][128] ------
__global__ __launch_bounds__(256)
void xposeW(const float* __restrict__ W1, const float* __restrict__ W2,
            const float* __restrict__ m1w1, const float* __restrict__ m1w2,
            const float* __restrict__ m2w1, const float* __restrict__ m2w2,
            __bf16* __restrict__ WT)
{
    int i = blockIdx.x * 256 + threadIdx.x;
    if (i >= 1344 * 128) return;
    int c = i >> 7, k = i & 127;
    const float* src; int lc, cr, K, st;
    if (c < 448)      { src = W1;   lc = c;        cr = 432; K = 107; st = 432; }
    else if (c < 896) { src = W2;   lc = c - 448;  cr = 416; K = 100; st = 416; }
    else if (c < 1024){ src = m1w1; lc = c - 896;  cr = 100; K = 107; st = 100; }
    else if (c < 1152){ src = m1w2; lc = c - 1024; cr = 100; K = 100; st = 100; }
    else if (c < 1216){ src = m2w1; lc = c - 1152; cr = 64;  K = 100; st = 64;  }
    else              { src = m2w2; lc = c - 1216; cr = 100; K = 64;  st = 100; }
    float v = (lc < cr && k < K) ? src[k * st + lc] : 0.f;
    WT[i] = (__bf16)v;
}

extern "C" void kernel_launch(void* const* d_in, const int* in_sizes, int n_in,
                              void* d_out, int out_size, void* d_ws, size_t ws_size,
                              hipStream_t stream)
{
    const float* x    = (const float*)d_in[0];
    const int*   eidx = (const int*)d_in[1];
    const float* eatt = (const float*)d_in[2];
    const float* l1aw = (const float*)d_in[3];
    const float* l1ab = (const float*)d_in[4];
    const float* l1bw = (const float*)d_in[5];
    const float* l1bb = (const float*)d_in[6];
    const float* m1w1 = (const float*)d_in[7];
    const float* m1b1 = (const float*)d_in[8];
    const float* m1w2 = (const float*)d_in[9];
    const float* m1b2 = (const float*)d_in[10];
    const float* l2aw = (const float*)d_in[11];
    const float* l2ab = (const float*)d_in[12];
    const float* l2bw = (const float*)d_in[13];
    const float* l2bb = (const float*)d_in[14];
    const float* m2w1 = (const float*)d_in[15];
    const float* m2b1 = (const float*)d_in[16];
    const float* m2w2 = (const float*)d_in[17];
    const float* m2b2 = (const float*)d_in[18];
    float* out = (float*)d_out;

    // workspace layout (4-byte units), ~450 MB
    float*  ws   = (float*)d_ws;
    __bf16* NTbf = (__bf16*)ws;                         // 50000*432 bf16
    float*  bufA = ws + 10800000;                       // 50000*112 fp32
    float*  bufC = bufA + 5600000;                      // 50000*100 fp32 (h)
    float*  W1   = bufC + 5000000;                      // 46,224
    float*  b1v  = W1 + 46224;                          // 432
    float*  W2   = b1v + 432;                           // 41,600
    float*  b2v  = W2 + 41600;                          // 416
    __bf16* Wt   = (__bf16*)(b2v + 416);                // 4*128*128 bf16
    __bf16* WT   = Wt + 65536;                          // 1344*128 bf16
    int*    off  = (int*)(WT + 172032);                 // 100,000
    int*    cur  = off + NN2;                           // 100,000
    int*    bsum = cur + NN2;                           // 512
    int*    srcp = bsum + 512;                          // 800,000
    int*    eord = srcp + NE;                           // 800,000
    __bf16* MT1  = (__bf16*)(eord + NE);                // NE*112 bf16
    __bf16* MT2  = MT1 + (size_t)NE * 112;              // NE*112 bf16
    float*  bufB = (float*)MT1;                         // t1/t2 alias (MT1 consumed)

    const int* dst = eidx + NE;

    assemble<<<256, 256, 0, stream>>>(l1aw, l1ab, l1bw, l1bb, l2aw, l2ab, l2bw, l2bb,
                                      W1, b1v, W2, b2v, Wt);
    xposeW<<<672, 256, 0, stream>>>(W1, W2, m1w1, m1w2, m2w1, m2w2, WT);

    // ---- CSR build (dst-sorted, per half; emits srcp/eord) ----
    zero_ints<<<(NN2 + 255) / 256, 256, 0, stream>>>(cur, NN2);
    count_edges<<<(NE + 255) / 256, 256, 0, stream>>>(dst, cur);
    scan_blocks<<<(NN2 + 255) / 256, 256, 0, stream>>>(cur, off, bsum, NN2);
    scan_bsum<<<1, 512, 0, stream>>>(bsum, (NN2 + 255) / 256);
    scan_add<<<(NN2 + 255) / 256, 256, 0, stream>>>(off, bsum, cur, NN2);
    scatter_edges<<<(NE + 255) / 256, 256, 0, stream>>>(eidx, cur, srcp, eord);

    // ---- both convs' edge mid-GEMMs (A gathered once, reused) ----
    mt_both<<<6250, 256, 0, stream>>>(eatt, eord, Wt, MT1, MT2);

    const int AG = NN / 4;   // 12500 blocks: 4 waves x 1 node each

    // ---- conv1 ----
    mm_bf16t<107, true><<<dim3(391, 7), 256, 0, stream>>>(x, WT, b1v, NTbf,
                                                          NN, 432, 432, 1, 0);
    edge_aggr3<107, 432><<<AG, 256, 0, stream>>>(MT1, srcp, off, NTbf, x, bufA,
                                                 0, 108, 324, 216);
    mm_bf16t<112, false><<<dim3(391, 2), 256, 0, stream>>>(bufA, WT + 896 * 128,
                                                           m1b1, bufB, NN, 100, 100, 1, 1);
    mm_bf16t<100, false><<<dim3(391, 2), 256, 0, stream>>>(bufB, WT + 1024 * 128,
                                                           m1b2, bufC, NN, 100, 100, 1, 1);

    // ---- conv2 ----  (h in bufC)
    mm_bf16t<100, true><<<dim3(391, 7), 256, 0, stream>>>(bufC, WT + 448 * 128,
                                                          b2v, NTbf, NN, 416, 416, 1, 0);
    edge_aggr3<100, 416><<<AG, 256, 0, stream>>>(MT2, srcp, off, NTbf, bufC, bufA,
                                                 0, 104, 312, 208);
    mm_bf16t<112, false><<<dim3(391, 1), 256, 0, stream>>>(bufA, WT + 1152 * 128,
                                                           m2b1, bufB, NN, 64, 64, 1, 1);
    mm_bf16t<64, false><<<dim3(391, 2), 256, 0, stream>>>(bufB, WT + 1216 * 128,
                                                          m2b2, out, NN, 100, 100, 1, 0);
}

// Round 20
// 759.144 us; speedup vs baseline: 3.0666x; 1.0032x over previous
//
#include <hip/hip_runtime.h>

// RuleGraphNet: 2x TripleConv(+mlp), N=50000 nodes, E=800000 edges.
// Pipeline: BOTH convs' edge mid-GEMMs in one dispatch (mt_both: 128-row
// blocks, wave owns 32 rows x ALL 112 cols -> each eatt row gathered once by
// 4 lanes; A fragments converted bf16 once, reused for conv1 AND conv2;
// per-n-tile W/C register blocking; wave-private LDS C-staging + copy-out,
// no barriers); MT1/MT2 CSR-ordered -> sequential aggregation; NT bf16;
// aggregation wave owns 1 dst node, lane owns a column pair, register
// accumulation over both phases, self fused. All dense GEMMs use
// pre-transposed bf16 weight tables, single-tile blocks (RT=1).

#define NN 50000
#define NE 800000
#define EHALF 400000
#define NN2 100000
#define GB 8            // edges batched per gather group

typedef __attribute__((ext_vector_type(4))) float  f32x4;
typedef __attribute__((ext_vector_type(8))) __bf16 bf16x8;
typedef __attribute__((ext_vector_type(4))) __bf16 bf16x4;

__device__ __forceinline__ float bf16lo(unsigned u) {
    union { unsigned u; float f; } c; c.u = u << 16; return c.f;
}
__device__ __forceinline__ float bf16hi(unsigned u) {
    union { unsigned u; float f; } c; c.u = u & 0xffff0000u; return c.f;
}

// ------- generic bf16 MFMA GEMM, W from pre-transposed bf16 table ---------
template<int K, bool OBF16>
__global__ __launch_bounds__(256)
void mm_bf16t(const float* __restrict__ A, const __bf16* __restrict__ Wtt,
              const float* __restrict__ bias, void* __restrict__ Outp,
              int M, int N, int ldo, int RT, int relu)
{
    __shared__ __align__(16) __bf16 et[128 * 128];
    const int t = threadIdx.x;
    const int lane = t & 63, w = t >> 6;
    const int mh = w & 1, nh = w >> 1;
    const int l15 = lane & 15, l4 = lane >> 4;
    const int cb = blockIdx.y * 64;

    bf16x8 wf[2][4];
    const int colbase = cb + nh * 32 + l15;
    #pragma unroll
    for (int nt = 0; nt < 2; ++nt)
        #pragma unroll
        for (int ks = 0; ks < 4; ++ks)
            wf[nt][ks] = *(const bf16x8*)(Wtt + (colbase + nt * 16) * 128 +
                                          ks * 32 + l4 * 8);
    float bv[2] = {0.f, 0.f};
    if (bias) {
        #pragma unroll
        for (int nt = 0; nt < 2; ++nt) {
            int col = colbase + nt * 16;
            if (col < N) bv[nt] = bias[col];
        }
    }

    for (int it = 0; it < RT; ++it) {
        const int row0 = (blockIdx.x * RT + it) * 128;
        if (row0 >= M) break;
        __syncthreads();
        if constexpr (K % 4 == 0) {
            constexpr int QK = K / 4;
            for (int i = t; i < 128 * QK; i += 256) {
                int row = i / QK, q = i - row * QK;
                int gr = row0 + row;
                float4 v = {0.f, 0.f, 0.f, 0.f};
                if (gr < M) v = *(const float4*)(A + (size_t)gr * K + q * 4);
                bf16x4 b;
                b[0] = (__bf16)v.x; b[1] = (__bf16)v.y;
                b[2] = (__bf16)v.z; b[3] = (__bf16)v.w;
                *(bf16x4*)(et + row * 128 + ((q * 4) ^ ((row & 7) << 3))) = b;
            }
            constexpr int QP = (128 - K) / 4;
            if constexpr (QP > 0) {
                for (int i = t; i < 128 * QP; i += 256) {
                    int row = i / QP, q = QK + (i - (i / QP) * QP);
                    bf16x4 z;
                    z[0] = (__bf16)0.f; z[1] = (__bf16)0.f;
                    z[2] = (__bf16)0.f; z[3] = (__bf16)0.f;
                    *(bf16x4*)(et + row * 128 + ((q * 4) ^ ((row & 7) << 3))) = z;
                }
            }
        } else {
            for (int i = t; i < 128 * 128; i += 256) {
                int row = i >> 7, k = i & 127;
                int gr = row0 + row;
                float v = (k < K && gr < M) ? A[(size_t)gr * K + k] : 0.f;
                et[row * 128 + (k ^ ((row & 7) << 3))] = (__bf16)v;
            }
        }
        __syncthreads();

        f32x4 c[4][2] = {};
        #pragma unroll
        for (int ks = 0; ks < 4; ++ks) {
            #pragma unroll
            for (int mt = 0; mt < 4; ++mt) {
                int arow = mh * 64 + mt * 16 + l15;
                bf16x8 a = *(const bf16x8*)(et + arow * 128 +
                                            ((ks * 32 + l4 * 8) ^ ((l15 & 7) << 3)));
                c[mt][0] = __builtin_amdgcn_mfma_f32_16x16x32_bf16(a, wf[0][ks], c[mt][0], 0, 0, 0);
                c[mt][1] = __builtin_amdgcn_mfma_f32_16x16x32_bf16(a, wf[1][ks], c[mt][1], 0, 0, 0);
            }
        }

        #pragma unroll
        for (int mt = 0; mt < 4; ++mt) {
            #pragma unroll
            for (int nt = 0; nt < 2; ++nt) {
                int col = colbase + nt * 16;
                #pragma unroll
                for (int r = 0; r < 4; ++r) {
                    int row = row0 + mh * 64 + mt * 16 + l4 * 4 + r;
                    if constexpr (OBF16) {
                        if (row < M && col < ldo)
                            ((__bf16*)Outp)[(size_t)row * ldo + col] =
                                (__bf16)(c[mt][nt][r] + bv[nt]);
                    } else {
                        if (row < M && col < N) {
                            float v = c[mt][nt][r] + bv[nt];
                            if (relu) v = fmaxf(v, 0.f);
                            ((float*)Outp)[(size_t)row * ldo + col] = v;
                        }
                    }
                }
            }
        }
    }
}

// ---------------- CSR build (edges sorted by dst, per half) ----------------
__global__ void zero_ints(int* __restrict__ p, int n)
{
    int i = blockIdx.x * 256 + threadIdx.x;
    if (i < n) p[i] = 0;
}

__global__ void count_edges(const int* __restrict__ dst, int* __restrict__ cnt)
{
    int e = blockIdx.x * 256 + threadIdx.x;
    if (e < NE) atomicAdd(&cnt[dst[e] + (e >= EHALF ? NN : 0)], 1);
}

__global__ void scan_blocks(const int* __restrict__ cnt, int* __restrict__ off,
                            int* __restrict__ bsum, int n)
{
    __shared__ int s[256];
    int t = threadIdx.x, g = blockIdx.x * 256 + t;
    int v = (g < n) ? cnt[g] : 0;
    s[t] = v; __syncthreads();
    for (int d = 1; d < 256; d <<= 1) {
        int add = (t >= d) ? s[t - d] : 0;
        __syncthreads();
        s[t] += add;
        __syncthreads();
    }
    if (g < n) off[g] = s[t] - v;
    if (t == 255) bsum[blockIdx.x] = s[255];
}

__global__ void scan_bsum(int* __restrict__ bsum, int nb)
{
    __shared__ int s[512];
    int t = threadIdx.x;
    int v = (t < nb) ? bsum[t] : 0;
    s[t] = v; __syncthreads();
    for (int d = 1; d < 512; d <<= 1) {
        int add = (t >= d) ? s[t - d] : 0;
        __syncthreads();
        s[t] += add;
        __syncthreads();
    }
    if (t < nb) bsum[t] = s[t] - v;
}

__global__ void scan_add(int* __restrict__ off, const int* __restrict__ bsum,
                         int* __restrict__ cur, int n)
{
    int g = blockIdx.x * 256 + threadIdx.x;
    if (g < n) { int o = off[g] + bsum[blockIdx.x]; off[g] = o; cur[g] = o; }
}

__global__ void scatter_edges(const int* __restrict__ eidx, int* __restrict__ cur,
                              int* __restrict__ srcp, int* __restrict__ eord)
{
    int e = blockIdx.x * 256 + threadIdx.x;
    if (e < NE) {
        int s = eidx[e], d = eidx[NE + e];
        int pos = atomicAdd(&cur[d + (e >= EHALF ? NN : 0)], 1);
        srcp[pos] = s;
        eord[pos] = e;
    }
}

// ----- mt_both: both convs' edge mid-GEMMs; wave owns 32 rows x 112 cols --
// grid 6250: block owns 128 CSR rows; half = rows<EHALF ? a : b. Wave w owns
// rows [w*32,+32): each eatt row gathered once (4 lanes, disjoint 32B k-
// segments), converted bf16 into af[2][4] registers, reused for conv1 and
// conv2. Per-n-tile blocking (wfn[4] + c4[2], nt loop 7 iters = 112 real
// cols). C staged in LDS (stride 116, <=2-way bank aliasing); wave-private
// copy-out, no barriers (in-wave LDS ordering via lgkmcnt).
__global__ __launch_bounds__(256)
void mt_both(const float* __restrict__ eatt,   // [NE][100] original order
             const int* __restrict__ eord,     // [NE] CSR pos -> edge id
             const __bf16* __restrict__ Wt,    // [4][128][128]
             __bf16* __restrict__ MT1,         // [NE][112] CSR order
             __bf16* __restrict__ MT2)         // [NE][112] CSR order
{
    __shared__ __align__(16) __bf16 ct[128 * 116];   // 29.7 KB
    const int t = threadIdx.x;
    const int lane = t & 63, w = t >> 6;
    const int l15 = lane & 15, l4 = lane >> 4;
    const size_t row0 = (size_t)blockIdx.x * 128;
    const int half = (row0 >= EHALF) ? 1 : 0;
    const int rbase = w * 32;

    // A fragments gathered + converted once (reused for both convs)
    bf16x8 af[2][4];
    {
        const float* ep[2];
        #pragma unroll
        for (int mt = 0; mt < 2; ++mt) {
            size_t row = row0 + rbase + mt * 16 + l15;
            ep[mt] = eatt + (size_t)eord[row] * 100;
        }
        #pragma unroll
        for (int ks = 0; ks < 4; ++ks) {
            const int bk = ks * 32 + l4 * 8;
            #pragma unroll
            for (int mt = 0; mt < 2; ++mt) {
                float4 v0 = {0.f, 0.f, 0.f, 0.f}, v1 = {0.f, 0.f, 0.f, 0.f};
                if (bk < 100)     v0 = *(const float4*)(ep[mt] + bk);
                if (bk + 4 < 100) v1 = *(const float4*)(ep[mt] + bk + 4);
                bf16x8 a;
                a[0] = (__bf16)v0.x; a[1] = (__bf16)v0.y;
                a[2] = (__bf16)v0.z; a[3] = (__bf16)v0.w;
                a[4] = (__bf16)v1.x; a[5] = (__bf16)v1.y;
                a[6] = (__bf16)v1.z; a[7] = (__bf16)v1.w;
                af[mt][ks] = a;
            }
        }
    }

    #pragma unroll 1
    for (int conv = 0; conv < 2; ++conv) {
        const __bf16* Wq = Wt + (size_t)(conv * 2 + half) * 16384;
        __bf16* MT = conv ? MT2 : MT1;

        #pragma unroll 1
        for (int nt = 0; nt < 7; ++nt) {
            const int col = nt * 16 + l15;
            bf16x8 wfn[4];
            #pragma unroll
            for (int ks = 0; ks < 4; ++ks)
                wfn[ks] = *(const bf16x8*)(Wq + col * 128 + ks * 32 + l4 * 8);
            f32x4 c4[2] = {};
            #pragma unroll
            for (int ks = 0; ks < 4; ++ks) {
                c4[0] = __builtin_amdgcn_mfma_f32_16x16x32_bf16(
                    af[0][ks], wfn[ks], c4[0], 0, 0, 0);
                c4[1] = __builtin_amdgcn_mfma_f32_16x16x32_bf16(
                    af[1][ks], wfn[ks], c4[1], 0, 0, 0);
            }
            #pragma unroll
            for (int mt = 0; mt < 2; ++mt)
                #pragma unroll
                for (int r = 0; r < 4; ++r)
                    ct[(rbase + mt * 16 + l4 * 4 + r) * 116 + col] =
                        (__bf16)c4[mt][r];
        }

        // wave-private copy-out: rows [rbase,+32) x cols 0..111
        __bf16* gout = MT + (row0 + rbase) * 112;
        #pragma unroll
        for (int k = 0; k < 14; ++k) {
            int i = lane + 64 * k;
            int row = i / 28, ch = i - row * 28;
            *(uint2*)(gout + row * 112 + ch * 4) =
                *(const uint2*)(ct + (rbase + row) * 116 + ch * 4);
        }
    }
}

// ---------------- edge_aggr3: both phases, register accumulation ----------
template<int ND, int NTS>
__global__ __launch_bounds__(256)
void edge_aggr3(const __bf16* __restrict__ MT,    // [NE][112] CSR order
                const int* __restrict__ srcp,     // [NE] src per CSR position
                const int* __restrict__ off,      // [NN2]
                const __bf16* __restrict__ NT,    // [NN][NTS] bf16
                const float* __restrict__ self,   // [NN][ND] fp32
                float* __restrict__ aggr,         // [NN][112]
                int blkd0, int blks0, int blkd1, int blks1)
{
    const int t = threadIdx.x;
    const int lane = t & 63, wv = t >> 6;
    const int c0 = lane * 2;
    const bool a0 = c0 < ND, a1 = c0 + 1 < ND;
    const int n = blockIdx.x * 4 + wv;     // one node per wave

    float acc0 = 0.f, acc1 = 0.f;

    #pragma unroll
    for (int phase = 0; phase < 2; ++phase) {
        const int blkd = phase ? blkd1 : blkd0;
        const int blks = phase ? blks1 : blks0;
        const int idx = phase * NN + n;
        const int pb = off[idx];
        const int pe = (idx + 1 == NN2) ? NE : off[idx + 1];

        float nd0 = 0.f, nd1 = 0.f;
        if (a0) {
            unsigned nd = *(const unsigned*)(NT + (size_t)n * NTS + blkd + c0);
            nd0 = bf16lo(nd); nd1 = bf16hi(nd);
        }

        for (int p = pb; p < pe; p += GB) {
            int ok[GB], ss[GB];
            #pragma unroll
            for (int i = 0; i < GB; ++i) {
                int pp = p + i;
                ok[i] = pp < pe;
                ss[i] = ok[i] ? srcp[pp] : 0;
            }
            unsigned mtw[GB], nsw[GB];
            #pragma unroll
            for (int i = 0; i < GB; ++i) {
                mtw[i] = 0u; nsw[i] = 0u;
                if (ok[i] && a0) {
                    mtw[i] = *(const unsigned*)(MT + (size_t)(p + i) * 112 + c0);
                    nsw[i] = *(const unsigned*)(NT + (size_t)ss[i] * NTS + blks + c0);
                }
            }
            #pragma unroll
            for (int i = 0; i < GB; ++i) {
                if (!ok[i]) continue;             // wave-uniform
                acc0 += fmaxf(bf16lo(mtw[i]) + nd0 + bf16lo(nsw[i]), 0.f);
                acc1 += fmaxf(bf16hi(mtw[i]) + nd1 + bf16hi(nsw[i]), 0.f);
            }
        }
    }

    if (c0 < 112) {
        const size_t g0 = (size_t)n * 112 + c0;
        aggr[g0]     = a0 ? (acc0 + self[(size_t)n * ND + c0])     : 0.f;
        aggr[g0 + 1] = a1 ? (acc1 + self[(size_t)n * ND + c0 + 1]) : 0.f;
    }
}

// ---- weight assembly: padded concat blocks + transposed mid blocks -------
__global__ void assemble(const float* __restrict__ l1a, const float* __restrict__ l1ab,
                         const float* __restrict__ l1b, const float* __restrict__ l1bb,
                         const float* __restrict__ l2a, const float* __restrict__ l2ab,
                         const float* __restrict__ l2b, const float* __restrict__ l2bb,
                         float* __restrict__ W1, float* __restrict__ b1,
                         float* __restrict__ W2, float* __restrict__ b2,
                         __bf16* __restrict__ Wt)
{
    int i = blockIdx.x * 256 + threadIdx.x;
    if (i < 107 * 432) {
        int k = i / 432, c = i % 432;
        int q = c / 108, cc = c - q * 108;
        float v = 0.f;
        if (cc < 107) {
            if (q == 0)      v = l1a[k * 107 + cc];
            else if (q == 1) v = l1a[(207 + k) * 107 + cc];
            else if (q == 2) v = l1b[k * 107 + cc];
            else             v = l1b[(207 + k) * 107 + cc];
        }
        W1[i] = v;
    }
    if (i < 432) {
        int q = i / 108, cc = i - q * 108;
        b1[i] = (cc < 107) ? (q == 0 ? l1ab[cc] : (q == 3 ? l1bb[cc] : 0.f)) : 0.f;
    }
    if (i < 100 * 416) {
        int k = i / 416, c = i % 416;
        int q = c / 104, cc = c - q * 104;
        float v = 0.f;
        if (cc < 100) {
            if (q == 0)      v = l2a[k * 100 + cc];
            else if (q == 1) v = l2a[(200 + k) * 100 + cc];
            else if (q == 2) v = l2b[k * 100 + cc];
            else             v = l2b[(200 + k) * 100 + cc];
        }
        W2[i] = v;
    }
    if (i < 416) {
        int q = i / 104, cc = i - q * 104;
        b2[i] = (cc < 100) ? (q == 0 ? l2ab[cc] : (q == 3 ? l2bb[cc] : 0.f)) : 0.f;
    }
    if (i < 4 * 128 * 128) {
        int q = i >> 14, col = (i >> 7) & 127, k = i & 127;
        const float* Wm = (q == 0) ? l1a + 107 * 107 :
                          (q == 1) ? l1b + 107 * 107 :
                          (q == 2) ? l2a + 100 * 100 : l2b + 100 * 100;
        int ND = (q < 2) ? 107 : 100;
        float v = (k < 100 && col < ND) ? Wm[k * ND + col] : 0.f;
        Wt[i] = (__bf16)v;
    }
}

// ---- xposeW: transpose all dense-GEMM weights into bf16 [1344][128] ------
__global__ __launch_bounds__(256)
void xposeW(const float* __restrict__ W1, const float* __restrict__ W2,
            const float* __restrict__ m1w1, const float* __restrict__ m1w2,
            const float* __restrict__ m2w1, const float* __restrict__ m2w2,
            __bf16* __restrict__ WT)
{
    int i = blockIdx.x * 256 + threadIdx.x;
    if (i >= 1344 * 128) return;
    int c = i >> 7, k = i & 127;
    const float* src; int lc, cr, K, st;
    if (c < 448)      { src = W1;   lc = c;        cr = 432; K = 107; st = 432; }
    else if (c < 896) { src = W2;   lc = c - 448;  cr = 416; K = 100; st = 416; }
    else if (c < 1024){ src = m1w1; lc = c - 896;  cr = 100; K = 107; st = 100; }
    else if (c < 1152){ src = m1w2; lc = c - 1024; cr = 100; K = 100; st = 100; }
    else if (c < 1216){ src = m2w1; lc = c - 1152; cr = 64;  K = 100; st = 64;  }
    else              { src = m2w2; lc = c - 1216; cr = 100; K = 64;  st = 100; }
    float v = (lc < cr && k < K) ? src[k * st + lc] : 0.f;
    WT[i] = (__bf16)v;
}

extern "C" void kernel_launch(void* const* d_in, const int* in_sizes, int n_in,
                              void* d_out, int out_size, void* d_ws, size_t ws_size,
                              hipStream_t stream)
{
    const float* x    = (const float*)d_in[0];
    const int*   eidx = (const int*)d_in[1];
    const float* eatt = (const float*)d_in[2];
    const float* l1aw = (const float*)d_in[3];
    const float* l1ab = (const float*)d_in[4];
    const float* l1bw = (const float*)d_in[5];
    const float* l1bb = (const float*)d_in[6];
    const float* m1w1 = (const float*)d_in[7];
    const float* m1b1 = (const float*)d_in[8];
    const float* m1w2 = (const float*)d_in[9];
    const float* m1b2 = (const float*)d_in[10];
    const float* l2aw = (const float*)d_in[11];
    const float* l2ab = (const float*)d_in[12];
    const float* l2bw = (const float*)d_in[13];
    const float* l2bb = (const float*)d_in[14];
    const float* m2w1 = (const float*)d_in[15];
    const float* m2b1 = (const float*)d_in[16];
    const float* m2w2 = (const float*)d_in[17];
    const float* m2b2 = (const float*)d_in[18];
    float* out = (float*)d_out;

    // workspace layout (4-byte units), ~450 MB
    float*  ws   = (float*)d_ws;
    __bf16* NTbf = (__bf16*)ws;                         // 50000*432 bf16
    float*  bufA = ws + 10800000;                       // 50000*112 fp32
    float*  bufC = bufA + 5600000;                      // 50000*100 fp32 (h)
    float*  W1   = bufC + 5000000;                      // 46,224
    float*  b1v  = W1 + 46224;                          // 432
    float*  W2   = b1v + 432;                           // 41,600
    float*  b2v  = W2 + 41600;                          // 416
    __bf16* Wt   = (__bf16*)(b2v + 416);                // 4*128*128 bf16
    __bf16* WT   = Wt + 65536;                          // 1344*128 bf16
    int*    off  = (int*)(WT + 172032);                 // 100,000
    int*    cur  = off + NN2;                           // 100,000
    int*    bsum = cur + NN2;                           // 512
    int*    srcp = bsum + 512;                          // 800,000
    int*    eord = srcp + NE;                           // 800,000
    __bf16* MT1  = (__bf16*)(eord + NE);                // NE*112 bf16
    __bf16* MT2  = MT1 + (size_t)NE * 112;              // NE*112 bf16
    float*  bufB = (float*)MT1;                         // t1/t2 alias (MT1 consumed)

    const int* dst = eidx + NE;

    assemble<<<256, 256, 0, stream>>>(l1aw, l1ab, l1bw, l1bb, l2aw, l2ab, l2bw, l2bb,
                                      W1, b1v, W2, b2v, Wt);
    xposeW<<<672, 256, 0, stream>>>(W1, W2, m1w1, m1w2, m2w1, m2w2, WT);

    // ---- CSR build (dst-sorted, per half; emits srcp/eord) ----
    zero_ints<<<(NN2 + 255) / 256, 256, 0, stream>>>(cur, NN2);
    count_edges<<<(NE + 255) / 256, 256, 0, stream>>>(dst, cur);
    scan_blocks<<<(NN2 + 255) / 256, 256, 0, stream>>>(cur, off, bsum, NN2);
    scan_bsum<<<1, 512, 0, stream>>>(bsum, (NN2 + 255) / 256);
    scan_add<<<(NN2 + 255) / 256, 256, 0, stream>>>(off, bsum, cur, NN2);
    scatter_edges<<<(NE + 255) / 256, 256, 0, stream>>>(eidx, cur, srcp, eord);

    // ---- both convs' edge mid-GEMMs (A gathered once, reused) ----
    mt_both<<<6250, 256, 0, stream>>>(eatt, eord, Wt, MT1, MT2);

    const int AG = NN / 4;   // 12500 blocks: 4 waves x 1 node each

    // ---- conv1 ----
    mm_bf16t<107, true><<<dim3(391, 7), 256, 0, stream>>>(x, WT, b1v, NTbf,
                                                          NN, 432, 432, 1, 0);
    edge_aggr3<107, 432><<<AG, 256, 0, stream>>>(MT1, srcp, off, NTbf, x, bufA,
                                                 0, 108, 324, 216);
    mm_bf16t<112, false><<<dim3(391, 2), 256, 0, stream>>>(bufA, WT + 896 * 128,
                                                           m1b1, bufB, NN, 100, 100, 1, 1);
    mm_bf16t<100, false><<<dim3(391, 2), 256, 0, stream>>>(bufB, WT + 1024 * 128,
                                                           m1b2, bufC, NN, 100, 100, 1, 1);

    // ---- conv2 ----  (h in bufC)
    mm_bf16t<100, true><<<dim3(391, 7), 256, 0, stream>>>(bufC, WT + 448 * 128,
                                                          b2v, NTbf, NN, 416, 416, 1, 0);
    edge_aggr3<100, 416><<<AG, 256, 0, stream>>>(MT2, srcp, off, NTbf, bufC, bufA,
                                                 0, 104, 312, 208);
    mm_bf16t<112, false><<<dim3(391, 1), 256, 0, stream>>>(bufA, WT + 1152 * 128,
                                                           m2b1, bufB, NN, 64, 64, 1, 1);
    mm_bf16t<64, false><<<dim3(391, 2), 256, 0, stream>>>(bufB, WT + 1216 * 128,
                                                          m2b2, out, NN, 100, 100, 1, 0);
}